// Round 13
// baseline (274.646 us; speedup 1.0000x reference)
//
#include <hip/hip_runtime.h>

#define N_NODES 100000
#define N_EDGES 1600000
#define IN_C 32
#define HID_C 64
#define OUT_C 32

#define EPB 1024                                 // edges per hist/place block
#define NBLK ((N_EDGES + EPB - 1) / EPB)         // 1563
#define BSH 8                                    // 256 nodes per bucket
#define BKN (1 << BSH)
#define NB ((N_NODES + BKN - 1) / BKN)           // 391

typedef __attribute__((ext_vector_type(8))) short bf16x8;
typedef __attribute__((ext_vector_type(8))) unsigned short u16x8;
typedef __attribute__((ext_vector_type(4))) float f32x4;

__device__ __forceinline__ unsigned short f2bf(float f) {
    unsigned u = __float_as_uint(f);
    return (unsigned short)((u + 0x7fffu + ((u >> 16) & 1u)) >> 16);
}
__device__ __forceinline__ float bf2f(unsigned short h) {
    return __uint_as_float((unsigned)h << 16);
}

// ---- pass A: bucket histogram (LDS only) + fused x->bf16 split cast -----
// x is cast into two physically separate half-tables xbA (ch 0-15) and
// xbB (ch 16-31), 3.2 MB each, so each gather phase's working set fits a
// 4 MB per-XCD L2 and halves don't share cache lines.
__global__ __launch_bounds__(256) void bucket_hist_kernel(
    const int* __restrict__ dst, int* __restrict__ gh,
    const float* __restrict__ x, ushort* __restrict__ xbA,
    ushort* __restrict__ xbB) {
    int ci = blockIdx.x * 256 + threadIdx.x;     // one thread per 8 floats
    if (ci < N_NODES * IN_C / 8) {
        int n = ci >> 2;
        int oc = ci & 3;                          // octet within row
        const float4* p = (const float4*)&x[(size_t)ci * 8];
        float4 a = p[0], b = p[1];
        u16x8 o;
        o[0] = f2bf(a.x); o[1] = f2bf(a.y); o[2] = f2bf(a.z); o[3] = f2bf(a.w);
        o[4] = f2bf(b.x); o[5] = f2bf(b.y); o[6] = f2bf(b.z); o[7] = f2bf(b.w);
        ushort* dstp = (oc < 2) ? xbA : xbB;
        *(u16x8*)&dstp[(size_t)n * 16 + (oc & 1) * 8] = o;
    }

    __shared__ int lh[NB];
    for (int i = threadIdx.x; i < NB; i += 256) lh[i] = 0;
    __syncthreads();
    int base = blockIdx.x * EPB;
#pragma unroll
    for (int j = 0; j < EPB / 256; ++j) {
        int e = base + j * 256 + threadIdx.x;
        if (e < N_EDGES) atomicAdd(&lh[dst[e] >> BSH], 1);
    }
    __syncthreads();
    for (int i = threadIdx.x; i < NB; i += 256)
        gh[i * NBLK + blockIdx.x] = lh[i];
}

__global__ void cast_w_kernel(const float* __restrict__ w1l,
                              const float* __restrict__ w1r,
                              const float* __restrict__ w2l,
                              const float* __restrict__ w2r,
                              ushort* __restrict__ wb) {
    for (int i = threadIdx.x; i < 8192; i += 256) {
        float v;
        if (i < 2048) v = w1l[i];
        else if (i < 4096) v = w1r[i - 2048];
        else if (i < 6144) v = w2l[i - 4096];
        else v = w2r[i - 6144];
        wb[i] = f2bf(v);
    }
}

// ---- pass B: per-bucket exclusive scan of gh across blocks + totals -----
__global__ __launch_bounds__(256) void bucket_scan_kernel(
    int* __restrict__ gh, int* __restrict__ btot) {
    int b = blockIdx.x;
    int t = threadIdx.x;
    __shared__ int ssum[256];
    int v[7];
    int base = t * 7;
    int s = 0;
#pragma unroll
    for (int j = 0; j < 7; ++j) {
        int idx = base + j;
        int val = (idx < NBLK) ? gh[b * NBLK + idx] : 0;
        v[j] = s;
        s += val;
    }
    ssum[t] = s;
    __syncthreads();
    for (int o = 1; o < 256; o <<= 1) {
        int val = (t >= o) ? ssum[t - o] : 0;
        __syncthreads();
        ssum[t] += val;
        __syncthreads();
    }
    int texcl = ssum[t] - s;
#pragma unroll
    for (int j = 0; j < 7; ++j) {
        int idx = base + j;
        if (idx < NBLK) gh[b * NBLK + idx] = texcl + v[j];
    }
    if (t == 255) btot[b] = ssum[255];
}

// ---- pass C: scan bucket totals -> bucket bases -------------------------
__global__ void base_scan_kernel(const int* __restrict__ btot,
                                 int* __restrict__ bbase) {
    int acc = 0;
    for (int i = 0; i < NB; ++i) { bbase[i] = acc; acc += btot[i]; }
    bbase[NB] = acc;
}

// ---- pass D: place packed (src<<8 | dst&255) into bucket-sorted tmp -----
__global__ __launch_bounds__(256) void bucket_place_kernel(
    const int* __restrict__ src, const int* __restrict__ dst,
    const int* __restrict__ gh, const int* __restrict__ bbase,
    unsigned* __restrict__ tmp) {
    __shared__ int cur[NB];
    for (int i = threadIdx.x; i < NB; i += 256)
        cur[i] = bbase[i] + gh[i * NBLK + blockIdx.x];
    __syncthreads();
    int base = blockIdx.x * EPB;
#pragma unroll
    for (int j = 0; j < EPB / 256; ++j) {
        int e = base + j * 256 + threadIdx.x;
        if (e < N_EDGES) {
            int d = dst[e];
            int slot = atomicAdd(&cur[d >> BSH], 1);
            tmp[slot] = ((unsigned)src[e] << 8) | (unsigned)(d & (BKN - 1));
        }
    }
}

// ---- pass E: per-bucket counts + rowptr + perm (all LDS) ----------------
__global__ __launch_bounds__(512) void count_place_kernel(
    const unsigned* __restrict__ tmp, const int* __restrict__ bbase,
    int* __restrict__ counts, int* __restrict__ rowptr,
    int* __restrict__ perm) {
    __shared__ int lcnt[BKN];
    __shared__ int sscan[BKN];
    __shared__ int cur[BKN];
    int b = blockIdx.x;
    int tid = threadIdx.x;
    int start = bbase[b], end = bbase[b + 1];
    if (tid < BKN) lcnt[tid] = 0;
    __syncthreads();
    for (int i = start + tid; i < end; i += 512)
        atomicAdd(&lcnt[tmp[i] & (BKN - 1)], 1);
    __syncthreads();
    if (tid < BKN) sscan[tid] = lcnt[tid];
    __syncthreads();
    for (int o = 1; o < BKN; o <<= 1) {
        int v = 0;
        if (tid < BKN && tid >= o) v = sscan[tid - o];
        __syncthreads();
        if (tid < BKN) sscan[tid] += v;
        __syncthreads();
    }
    if (tid < BKN) {
        int excl = sscan[tid] - lcnt[tid] + start;
        cur[tid] = excl;
        int n = (b << BSH) + tid;
        if (n < N_NODES) { rowptr[n] = excl; counts[n] = lcnt[tid]; }
    }
    __syncthreads();
    for (int i = start + tid; i < end; i += 512) {
        unsigned p = tmp[i];
        int slot = atomicAdd(&cur[p & (BKN - 1)], 1);
        perm[slot] = (int)(p >> 8);
    }
}

// ---- gather-mean over one 16-channel half-table -------------------------
// 4 nodes/wave, 32 edge slots (g) x 2 channel octets (q); batched
// dependency chain. Half-table is 3.2 MB -> L2-resident per XCD.
__global__ __launch_bounds__(256) void gather_mean_half_kernel(
    const ushort* __restrict__ xh, const int* __restrict__ rowptr,
    const int* __restrict__ counts, const int* __restrict__ perm,
    ushort* __restrict__ mh) {
    int lane = threadIdx.x & 63;
    int wid = threadIdx.x >> 6;
    int nb = (blockIdx.x * 4 + wid) * 4;
    if (nb >= N_NODES) return;
    int g = lane >> 1;          // edge slot 0..31
    int q = lane & 1;           // channel octet

    int st[4], cn[4];
#pragma unroll
    for (int k = 0; k < 4; ++k) {
        int n = nb + k;
        bool v = n < N_NODES;
        st[k] = v ? rowptr[n] : 0;
        cn[k] = v ? counts[n] : 0;
    }
    int p[4];
#pragma unroll
    for (int k = 0; k < 4; ++k)
        p[k] = (g < cn[k]) ? perm[st[k] + g] : -1;

    float acc[4][8];
#pragma unroll
    for (int k = 0; k < 4; ++k)
#pragma unroll
        for (int j = 0; j < 8; ++j) acc[k][j] = 0.f;

#pragma unroll
    for (int k = 0; k < 4; ++k) {
        if (p[k] >= 0) {
            u16x8 v = *(const u16x8*)&xh[(size_t)p[k] * 16 + q * 8];
#pragma unroll
            for (int j = 0; j < 8; ++j) acc[k][j] += bf2f(v[j]);
        }
    }
#pragma unroll
    for (int k = 0; k < 4; ++k) {
        for (int i = st[k] + g + 32; i < st[k] + cn[k]; i += 32) {
            int idx = perm[i];
            u16x8 v = *(const u16x8*)&xh[(size_t)idx * 16 + q * 8];
#pragma unroll
            for (int j = 0; j < 8; ++j) acc[k][j] += bf2f(v[j]);
        }
    }

#pragma unroll
    for (int k = 0; k < 4; ++k)
#pragma unroll
        for (int off = 2; off < 64; off <<= 1)
#pragma unroll
            for (int j = 0; j < 8; ++j)
                acc[k][j] += __shfl_xor(acc[k][j], off, 64);

    if (g == 0) {
#pragma unroll
        for (int k = 0; k < 4; ++k) {
            int n = nb + k;
            if (n < N_NODES) {
                float inv = 1.0f / fmaxf((float)cn[k], 1.0f);
                u16x8 o;
#pragma unroll
                for (int j = 0; j < 8; ++j) o[j] = f2bf(acc[k][j] * inv);
                *(u16x8*)&mh[(size_t)n * 16 + q * 8] = o;
            }
        }
    }
}

// ---- gather-final over one half: out half = mean(t-half) + r-half -------
__global__ __launch_bounds__(256) void gather_final_half_kernel(
    const ushort* __restrict__ th, const int* __restrict__ rowptr,
    const int* __restrict__ counts, const int* __restrict__ perm,
    const float* __restrict__ rh, float* __restrict__ out, int half) {
    int lane = threadIdx.x & 63;
    int wid = threadIdx.x >> 6;
    int nb = (blockIdx.x * 4 + wid) * 4;
    if (nb >= N_NODES) return;
    int g = lane >> 1;
    int q = lane & 1;

    int st[4], cn[4];
#pragma unroll
    for (int k = 0; k < 4; ++k) {
        int n = nb + k;
        bool v = n < N_NODES;
        st[k] = v ? rowptr[n] : 0;
        cn[k] = v ? counts[n] : 0;
    }
    int p[4];
#pragma unroll
    for (int k = 0; k < 4; ++k)
        p[k] = (g < cn[k]) ? perm[st[k] + g] : -1;

    float acc[4][8];
#pragma unroll
    for (int k = 0; k < 4; ++k)
#pragma unroll
        for (int j = 0; j < 8; ++j) acc[k][j] = 0.f;

#pragma unroll
    for (int k = 0; k < 4; ++k) {
        if (p[k] >= 0) {
            u16x8 v = *(const u16x8*)&th[(size_t)p[k] * 16 + q * 8];
#pragma unroll
            for (int j = 0; j < 8; ++j) acc[k][j] += bf2f(v[j]);
        }
    }
#pragma unroll
    for (int k = 0; k < 4; ++k) {
        for (int i = st[k] + g + 32; i < st[k] + cn[k]; i += 32) {
            int idx = perm[i];
            u16x8 v = *(const u16x8*)&th[(size_t)idx * 16 + q * 8];
#pragma unroll
            for (int j = 0; j < 8; ++j) acc[k][j] += bf2f(v[j]);
        }
    }

#pragma unroll
    for (int k = 0; k < 4; ++k)
#pragma unroll
        for (int off = 2; off < 64; off <<= 1)
#pragma unroll
            for (int j = 0; j < 8; ++j)
                acc[k][j] += __shfl_xor(acc[k][j], off, 64);

    if (g == 0) {
#pragma unroll
        for (int k = 0; k < 4; ++k) {
            int n = nb + k;
            if (n < N_NODES) {
                float inv = 1.0f / fmaxf((float)cn[k], 1.0f);
                const float4* rp = (const float4*)&rh[(size_t)n * 16 + q * 8];
                float4 r0 = rp[0], r1 = rp[1];
                float4* op = (float4*)&out[(size_t)n * 32 + half * 16 + q * 8];
                op[0] = make_float4(acc[k][0] * inv + r0.x, acc[k][1] * inv + r0.y,
                                    acc[k][2] * inv + r0.z, acc[k][3] * inv + r0.w);
                op[1] = make_float4(acc[k][4] * inv + r1.x, acc[k][5] * inv + r1.y,
                                    acc[k][6] * inv + r1.z, acc[k][7] * inv + r1.w);
            }
        }
    }
}

// ---- MFMA transform: reads/writes split half-tables ---------------------
__global__ __launch_bounds__(256) void transform_mfma_kernel(
    const ushort* __restrict__ xbA, const ushort* __restrict__ xbB,
    const ushort* __restrict__ mbA, const ushort* __restrict__ mbB,
    const ushort* __restrict__ wb, const float* __restrict__ b1,
    const float* __restrict__ b2, ushort* __restrict__ tbA,
    ushort* __restrict__ tbB, float* __restrict__ rA,
    float* __restrict__ rB) {
    __shared__ ushort hlds[4][16 * 72];
    int lane = threadIdx.x & 63;
    int wid = threadIdx.x >> 6;
    int l15 = lane & 15, lhi = lane >> 4;

    const ushort* w1l = wb;
    const ushort* w1r = wb + 2048;
    const ushort* w2l = wb + 4096;
    const ushort* w2r = wb + 6144;

    bf16x8 B1l[4], B1r[4];
#pragma unroll
    for (int jt = 0; jt < 4; ++jt) {
        B1l[jt] = *(const bf16x8*)&w1l[(jt * 16 + l15) * 32 + 8 * lhi];
        B1r[jt] = *(const bf16x8*)&w1r[(jt * 16 + l15) * 32 + 8 * lhi];
    }
    bf16x8 B2l[2][2], B2r[2][2];
#pragma unroll
    for (int ct = 0; ct < 2; ++ct)
#pragma unroll
        for (int kc = 0; kc < 2; ++kc) {
            B2l[ct][kc] = *(const bf16x8*)&w2l[(ct * 16 + l15) * 64 + kc * 32 + 8 * lhi];
            B2r[ct][kc] = *(const bf16x8*)&w2r[(ct * 16 + l15) * 64 + kc * 32 + 8 * lhi];
        }
    float bias1[4];
#pragma unroll
    for (int jt = 0; jt < 4; ++jt) bias1[jt] = b1[jt * 16 + l15];
    float bias2[2] = { b2[l15], b2[16 + l15] };

    ushort* hl = hlds[wid];

#pragma unroll
    for (int chunk = 0; chunk < 2; ++chunk) {
        int n0 = blockIdx.x * 128 + wid * 32 + chunk * 16;
        int nrow = n0 + l15;
        bf16x8 Am = {}, Ax = {};
        if (nrow < N_NODES) {
            const ushort* ms = (lhi < 2) ? mbA : mbB;
            const ushort* xs = (lhi < 2) ? xbA : xbB;
            Am = *(const bf16x8*)&ms[(size_t)nrow * 16 + 8 * (lhi & 1)];
            Ax = *(const bf16x8*)&xs[(size_t)nrow * 16 + 8 * (lhi & 1)];
        }
#pragma unroll
        for (int jt = 0; jt < 4; ++jt) {
            f32x4 acc = {};
            acc = __builtin_amdgcn_mfma_f32_16x16x32_bf16(Am, B1l[jt], acc, 0, 0, 0);
            acc = __builtin_amdgcn_mfma_f32_16x16x32_bf16(Ax, B1r[jt], acc, 0, 0, 0);
#pragma unroll
            for (int reg = 0; reg < 4; ++reg) {
                float h = fmaxf(acc[reg] + bias1[jt], 0.0f);
                hl[(lhi * 4 + reg) * 72 + jt * 16 + l15] = f2bf(h);
            }
        }
        bf16x8 Ah0 = *(const bf16x8*)&hl[l15 * 72 + 8 * lhi];
        bf16x8 Ah1 = *(const bf16x8*)&hl[l15 * 72 + 32 + 8 * lhi];
#pragma unroll
        for (int ct = 0; ct < 2; ++ct) {
            f32x4 acc = {};
            acc = __builtin_amdgcn_mfma_f32_16x16x32_bf16(Ah0, B2l[ct][0], acc, 0, 0, 0);
            acc = __builtin_amdgcn_mfma_f32_16x16x32_bf16(Ah1, B2l[ct][1], acc, 0, 0, 0);
            ushort* tdst = ct ? tbB : tbA;
#pragma unroll
            for (int reg = 0; reg < 4; ++reg) {
                int nr = n0 + lhi * 4 + reg;
                if (nr < N_NODES)
                    tdst[(size_t)nr * 16 + l15] = f2bf(acc[reg]);
            }
        }
#pragma unroll
        for (int ct = 0; ct < 2; ++ct) {
            f32x4 acc = {};
            acc = __builtin_amdgcn_mfma_f32_16x16x32_bf16(Ah0, B2r[ct][0], acc, 0, 0, 0);
            acc = __builtin_amdgcn_mfma_f32_16x16x32_bf16(Ah1, B2r[ct][1], acc, 0, 0, 0);
            float* rdst = ct ? rB : rA;
#pragma unroll
            for (int reg = 0; reg < 4; ++reg) {
                int nr = n0 + lhi * 4 + reg;
                if (nr < N_NODES)
                    rdst[(size_t)nr * 16 + l15] = acc[reg] + bias2[ct];
            }
        }
    }
}

// ---- launch -------------------------------------------------------------

extern "C" void kernel_launch(void* const* d_in, const int* in_sizes, int n_in,
                              void* d_out, int out_size, void* d_ws, size_t ws_size,
                              hipStream_t stream) {
    const float* x   = (const float*)d_in[0];
    const float* W1l = (const float*)d_in[1];
    const float* W1r = (const float*)d_in[2];
    const float* b1  = (const float*)d_in[3];
    const float* W2l = (const float*)d_in[4];
    const float* W2r = (const float*)d_in[5];
    const float* b2  = (const float*)d_in[6];
    const int*   ei  = (const int*)d_in[7];   // [2, N_EDGES]
    const int* src = ei;
    const int* dst = ei + N_EDGES;

    char* ws = (char*)d_ws;
    int*      gh     = (int*)ws;             ws += (size_t)NB * NBLK * 4;
    int*      btot   = (int*)ws;             ws += (size_t)(NB + 8) * 4;
    int*      bbase  = (int*)ws;             ws += (size_t)(NB + 8) * 4;
    int*      counts = (int*)ws;             ws += (size_t)N_NODES * 4;
    int*      rowptr = (int*)ws;             ws += (size_t)N_NODES * 4;
    int*      perm   = (int*)ws;             ws += (size_t)N_EDGES * 4;
    unsigned* tmp    = (unsigned*)ws;        ws += (size_t)N_EDGES * 4;
    // mbA/mbB (3.2MB each) alias tmp (6.4MB): tmp dead after count_place.
    ushort*   mbA    = (ushort*)tmp;
    ushort*   mbB    = mbA + (size_t)N_NODES * 16;
    ushort*   xbA    = (ushort*)ws;          ws += (size_t)N_NODES * 16 * 2;
    ushort*   xbB    = (ushort*)ws;          ws += (size_t)N_NODES * 16 * 2;
    ushort*   wb     = (ushort*)ws;          ws += (size_t)8192 * 2;
    ushort*   tbA    = (ushort*)ws;          ws += (size_t)N_NODES * 16 * 2;
    ushort*   tbB    = (ushort*)ws;          ws += (size_t)N_NODES * 16 * 2;
    float*    rA     = (float*)ws;           ws += (size_t)N_NODES * 16 * 4;
    float*    rB     = (float*)ws;           ws += (size_t)N_NODES * 16 * 4;

    dim3 blk(256);
    int ggrid = (N_NODES + 15) / 16;   // 4 waves/block x 4 nodes/wave

    cast_w_kernel<<<1, blk, 0, stream>>>(W1l, W1r, W2l, W2r, wb);
    bucket_hist_kernel<<<NBLK, blk, 0, stream>>>(dst, gh, x, xbA, xbB);
    bucket_scan_kernel<<<NB, blk, 0, stream>>>(gh, btot);
    base_scan_kernel<<<1, 1, 0, stream>>>(btot, bbase);
    bucket_place_kernel<<<NBLK, blk, 0, stream>>>(src, dst, gh, bbase, tmp);
    count_place_kernel<<<NB, dim3(512), 0, stream>>>(tmp, bbase, counts, rowptr, perm);

    gather_mean_half_kernel<<<ggrid, blk, 0, stream>>>(xbA, rowptr, counts, perm, mbA);
    gather_mean_half_kernel<<<ggrid, blk, 0, stream>>>(xbB, rowptr, counts, perm, mbB);
    transform_mfma_kernel<<<(N_NODES + 127) / 128, blk, 0, stream>>>(
        xbA, xbB, mbA, mbB, wb, b1, b2, tbA, tbB, rA, rB);
    gather_final_half_kernel<<<ggrid, blk, 0, stream>>>(tbA, rowptr, counts, perm,
                                                       rA, (float*)d_out, 0);
    gather_final_half_kernel<<<ggrid, blk, 0, stream>>>(tbB, rowptr, counts, perm,
                                                       rB, (float*)d_out, 1);
}

// Round 14
// 161.943 us; speedup vs baseline: 1.6959x; 1.6959x over previous
//
#include <hip/hip_runtime.h>

#define N_NODES 100000
#define N_EDGES 1600000
#define IN_C 32
#define HID_C 64
#define OUT_C 32

#define EPB 1024                                 // edges per hist/place block
#define NBLK ((N_EDGES + EPB - 1) / EPB)         // 1563
#define BSH 8                                    // 256 nodes per bucket
#define BKN (1 << BSH)
#define NB ((N_NODES + BKN - 1) / BKN)           // 391

typedef __attribute__((ext_vector_type(8))) short bf16x8;
typedef __attribute__((ext_vector_type(8))) unsigned short u16x8;
typedef __attribute__((ext_vector_type(4))) float f32x4;

__device__ __forceinline__ unsigned short f2bf(float f) {
    unsigned u = __float_as_uint(f);
    return (unsigned short)((u + 0x7fffu + ((u >> 16) & 1u)) >> 16);
}
__device__ __forceinline__ float bf2f(unsigned short h) {
    return __uint_as_float((unsigned)h << 16);
}

// ---- pass A: bucket histogram (LDS only) + fused x->bf16 split cast -----
__global__ __launch_bounds__(256) void bucket_hist_kernel(
    const int* __restrict__ dst, int* __restrict__ gh,
    const float* __restrict__ x, ushort* __restrict__ xbA,
    ushort* __restrict__ xbB) {
    int ci = blockIdx.x * 256 + threadIdx.x;     // one thread per 8 floats
    if (ci < N_NODES * IN_C / 8) {
        int n = ci >> 2;
        int oc = ci & 3;                          // octet within row
        const float4* p = (const float4*)&x[(size_t)ci * 8];
        float4 a = p[0], b = p[1];
        u16x8 o;
        o[0] = f2bf(a.x); o[1] = f2bf(a.y); o[2] = f2bf(a.z); o[3] = f2bf(a.w);
        o[4] = f2bf(b.x); o[5] = f2bf(b.y); o[6] = f2bf(b.z); o[7] = f2bf(b.w);
        ushort* dstp = (oc < 2) ? xbA : xbB;
        *(u16x8*)&dstp[(size_t)n * 16 + (oc & 1) * 8] = o;
    }

    __shared__ int lh[NB];
    for (int i = threadIdx.x; i < NB; i += 256) lh[i] = 0;
    __syncthreads();
    int base = blockIdx.x * EPB;
#pragma unroll
    for (int j = 0; j < EPB / 256; ++j) {
        int e = base + j * 256 + threadIdx.x;
        if (e < N_EDGES) atomicAdd(&lh[dst[e] >> BSH], 1);
    }
    __syncthreads();
    for (int i = threadIdx.x; i < NB; i += 256)
        gh[i * NBLK + blockIdx.x] = lh[i];
}

__global__ void cast_w_kernel(const float* __restrict__ w1l,
                              const float* __restrict__ w1r,
                              const float* __restrict__ w2l,
                              const float* __restrict__ w2r,
                              ushort* __restrict__ wb) {
    for (int i = threadIdx.x; i < 8192; i += 256) {
        float v;
        if (i < 2048) v = w1l[i];
        else if (i < 4096) v = w1r[i - 2048];
        else if (i < 6144) v = w2l[i - 4096];
        else v = w2r[i - 6144];
        wb[i] = f2bf(v);
    }
}

// ---- pass B: per-bucket exclusive scan of gh across blocks + totals -----
__global__ __launch_bounds__(256) void bucket_scan_kernel(
    int* __restrict__ gh, int* __restrict__ btot) {
    int b = blockIdx.x;
    int t = threadIdx.x;
    __shared__ int ssum[256];
    int v[7];
    int base = t * 7;
    int s = 0;
#pragma unroll
    for (int j = 0; j < 7; ++j) {
        int idx = base + j;
        int val = (idx < NBLK) ? gh[b * NBLK + idx] : 0;
        v[j] = s;
        s += val;
    }
    ssum[t] = s;
    __syncthreads();
    for (int o = 1; o < 256; o <<= 1) {
        int val = (t >= o) ? ssum[t - o] : 0;
        __syncthreads();
        ssum[t] += val;
        __syncthreads();
    }
    int texcl = ssum[t] - s;
#pragma unroll
    for (int j = 0; j < 7; ++j) {
        int idx = base + j;
        if (idx < NBLK) gh[b * NBLK + idx] = texcl + v[j];
    }
    if (t == 255) btot[b] = ssum[255];
}

// ---- pass C: scan bucket totals -> bucket bases -------------------------
__global__ void base_scan_kernel(const int* __restrict__ btot,
                                 int* __restrict__ bbase) {
    int acc = 0;
    for (int i = 0; i < NB; ++i) { bbase[i] = acc; acc += btot[i]; }
    bbase[NB] = acc;
}

// ---- pass D: place packed (src<<8 | dst&255) into bucket-sorted tmp -----
__global__ __launch_bounds__(256) void bucket_place_kernel(
    const int* __restrict__ src, const int* __restrict__ dst,
    const int* __restrict__ gh, const int* __restrict__ bbase,
    unsigned* __restrict__ tmp) {
    __shared__ int cur[NB];
    for (int i = threadIdx.x; i < NB; i += 256)
        cur[i] = bbase[i] + gh[i * NBLK + blockIdx.x];
    __syncthreads();
    int base = blockIdx.x * EPB;
#pragma unroll
    for (int j = 0; j < EPB / 256; ++j) {
        int e = base + j * 256 + threadIdx.x;
        if (e < N_EDGES) {
            int d = dst[e];
            int slot = atomicAdd(&cur[d >> BSH], 1);
            tmp[slot] = ((unsigned)src[e] << 8) | (unsigned)(d & (BKN - 1));
        }
    }
}

// ---- pass E: per-bucket counts + rowptr + perm (all LDS) ----------------
__global__ __launch_bounds__(512) void count_place_kernel(
    const unsigned* __restrict__ tmp, const int* __restrict__ bbase,
    int* __restrict__ counts, int* __restrict__ rowptr,
    int* __restrict__ perm) {
    __shared__ int lcnt[BKN];
    __shared__ int sscan[BKN];
    __shared__ int cur[BKN];
    int b = blockIdx.x;
    int tid = threadIdx.x;
    int start = bbase[b], end = bbase[b + 1];
    if (tid < BKN) lcnt[tid] = 0;
    __syncthreads();
    for (int i = start + tid; i < end; i += 512)
        atomicAdd(&lcnt[tmp[i] & (BKN - 1)], 1);
    __syncthreads();
    if (tid < BKN) sscan[tid] = lcnt[tid];
    __syncthreads();
    for (int o = 1; o < BKN; o <<= 1) {
        int v = 0;
        if (tid < BKN && tid >= o) v = sscan[tid - o];
        __syncthreads();
        if (tid < BKN) sscan[tid] += v;
        __syncthreads();
    }
    if (tid < BKN) {
        int excl = sscan[tid] - lcnt[tid] + start;
        cur[tid] = excl;
        int n = (b << BSH) + tid;
        if (n < N_NODES) { rowptr[n] = excl; counts[n] = lcnt[tid]; }
    }
    __syncthreads();
    for (int i = start + tid; i < end; i += 512) {
        unsigned p = tmp[i];
        int slot = atomicAdd(&cur[p & (BKN - 1)], 1);
        perm[slot] = (int)(p >> 8);
    }
}

// ---- serial-per-lane gather over one 16-channel half-table --------------
// Lane owns (node, 8-ch octet): 2 lanes/node, 32 nodes/wave. NO cross-lane
// shuffles (the measured 39us/kernel LDS-pipe cost in r10-r13). Edge loop
// hand-pipelined in chunks of 4: batch perm loads -> 4 independent 16B
// feature loads (L2-resident: half-table is 3.2MB < 4MB L2/XCD).
__global__ __launch_bounds__(256) void gather_mean_half_kernel(
    const ushort* __restrict__ xh, const int* __restrict__ rowptr,
    const int* __restrict__ counts, const int* __restrict__ perm,
    ushort* __restrict__ mh) {
    int lane = threadIdx.x & 63;
    int wid = threadIdx.x >> 6;
    int n = (blockIdx.x * 4 + wid) * 32 + (lane >> 1);
    int q = lane & 1;
    if (n >= N_NODES) return;
    int st = rowptr[n];
    int cn = counts[n];

    float acc[8] = {0, 0, 0, 0, 0, 0, 0, 0};
    int i = 0;
    for (; i + 4 <= cn; i += 4) {
        int p0 = perm[st + i + 0];
        int p1 = perm[st + i + 1];
        int p2 = perm[st + i + 2];
        int p3 = perm[st + i + 3];
        u16x8 v0 = *(const u16x8*)&xh[(size_t)p0 * 16 + q * 8];
        u16x8 v1 = *(const u16x8*)&xh[(size_t)p1 * 16 + q * 8];
        u16x8 v2 = *(const u16x8*)&xh[(size_t)p2 * 16 + q * 8];
        u16x8 v3 = *(const u16x8*)&xh[(size_t)p3 * 16 + q * 8];
#pragma unroll
        for (int j = 0; j < 8; ++j)
            acc[j] += (bf2f(v0[j]) + bf2f(v1[j])) + (bf2f(v2[j]) + bf2f(v3[j]));
    }
    for (; i < cn; ++i) {
        int p = perm[st + i];
        u16x8 v = *(const u16x8*)&xh[(size_t)p * 16 + q * 8];
#pragma unroll
        for (int j = 0; j < 8; ++j) acc[j] += bf2f(v[j]);
    }

    float inv = 1.0f / fmaxf((float)cn, 1.0f);
    u16x8 o;
#pragma unroll
    for (int j = 0; j < 8; ++j) o[j] = f2bf(acc[j] * inv);
    *(u16x8*)&mh[(size_t)n * 16 + q * 8] = o;
}

// ---- serial-per-lane gather-final: out half = mean(t-half) + r-half -----
__global__ __launch_bounds__(256) void gather_final_half_kernel(
    const ushort* __restrict__ th, const int* __restrict__ rowptr,
    const int* __restrict__ counts, const int* __restrict__ perm,
    const float* __restrict__ rh, float* __restrict__ out, int half) {
    int lane = threadIdx.x & 63;
    int wid = threadIdx.x >> 6;
    int n = (blockIdx.x * 4 + wid) * 32 + (lane >> 1);
    int q = lane & 1;
    if (n >= N_NODES) return;
    int st = rowptr[n];
    int cn = counts[n];

    float acc[8] = {0, 0, 0, 0, 0, 0, 0, 0};
    int i = 0;
    for (; i + 4 <= cn; i += 4) {
        int p0 = perm[st + i + 0];
        int p1 = perm[st + i + 1];
        int p2 = perm[st + i + 2];
        int p3 = perm[st + i + 3];
        u16x8 v0 = *(const u16x8*)&th[(size_t)p0 * 16 + q * 8];
        u16x8 v1 = *(const u16x8*)&th[(size_t)p1 * 16 + q * 8];
        u16x8 v2 = *(const u16x8*)&th[(size_t)p2 * 16 + q * 8];
        u16x8 v3 = *(const u16x8*)&th[(size_t)p3 * 16 + q * 8];
#pragma unroll
        for (int j = 0; j < 8; ++j)
            acc[j] += (bf2f(v0[j]) + bf2f(v1[j])) + (bf2f(v2[j]) + bf2f(v3[j]));
    }
    for (; i < cn; ++i) {
        int p = perm[st + i];
        u16x8 v = *(const u16x8*)&th[(size_t)p * 16 + q * 8];
#pragma unroll
        for (int j = 0; j < 8; ++j) acc[j] += bf2f(v[j]);
    }

    float inv = 1.0f / fmaxf((float)cn, 1.0f);
    const float4* rp = (const float4*)&rh[(size_t)n * 16 + q * 8];
    float4 r0 = rp[0], r1 = rp[1];
    float4* op = (float4*)&out[(size_t)n * 32 + half * 16 + q * 8];
    op[0] = make_float4(acc[0] * inv + r0.x, acc[1] * inv + r0.y,
                        acc[2] * inv + r0.z, acc[3] * inv + r0.w);
    op[1] = make_float4(acc[4] * inv + r1.x, acc[5] * inv + r1.y,
                        acc[6] * inv + r1.z, acc[7] * inv + r1.w);
}

// ---- MFMA transform: reads/writes split half-tables ---------------------
__global__ __launch_bounds__(256) void transform_mfma_kernel(
    const ushort* __restrict__ xbA, const ushort* __restrict__ xbB,
    const ushort* __restrict__ mbA, const ushort* __restrict__ mbB,
    const ushort* __restrict__ wb, const float* __restrict__ b1,
    const float* __restrict__ b2, ushort* __restrict__ tbA,
    ushort* __restrict__ tbB, float* __restrict__ rA,
    float* __restrict__ rB) {
    __shared__ ushort hlds[4][16 * 72];
    int lane = threadIdx.x & 63;
    int wid = threadIdx.x >> 6;
    int l15 = lane & 15, lhi = lane >> 4;

    const ushort* w1l = wb;
    const ushort* w1r = wb + 2048;
    const ushort* w2l = wb + 4096;
    const ushort* w2r = wb + 6144;

    bf16x8 B1l[4], B1r[4];
#pragma unroll
    for (int jt = 0; jt < 4; ++jt) {
        B1l[jt] = *(const bf16x8*)&w1l[(jt * 16 + l15) * 32 + 8 * lhi];
        B1r[jt] = *(const bf16x8*)&w1r[(jt * 16 + l15) * 32 + 8 * lhi];
    }
    bf16x8 B2l[2][2], B2r[2][2];
#pragma unroll
    for (int ct = 0; ct < 2; ++ct)
#pragma unroll
        for (int kc = 0; kc < 2; ++kc) {
            B2l[ct][kc] = *(const bf16x8*)&w2l[(ct * 16 + l15) * 64 + kc * 32 + 8 * lhi];
            B2r[ct][kc] = *(const bf16x8*)&w2r[(ct * 16 + l15) * 64 + kc * 32 + 8 * lhi];
        }
    float bias1[4];
#pragma unroll
    for (int jt = 0; jt < 4; ++jt) bias1[jt] = b1[jt * 16 + l15];
    float bias2[2] = { b2[l15], b2[16 + l15] };

    ushort* hl = hlds[wid];

#pragma unroll
    for (int chunk = 0; chunk < 2; ++chunk) {
        int n0 = blockIdx.x * 128 + wid * 32 + chunk * 16;
        int nrow = n0 + l15;
        bf16x8 Am = {}, Ax = {};
        if (nrow < N_NODES) {
            const ushort* ms = (lhi < 2) ? mbA : mbB;
            const ushort* xs = (lhi < 2) ? xbA : xbB;
            Am = *(const bf16x8*)&ms[(size_t)nrow * 16 + 8 * (lhi & 1)];
            Ax = *(const bf16x8*)&xs[(size_t)nrow * 16 + 8 * (lhi & 1)];
        }
#pragma unroll
        for (int jt = 0; jt < 4; ++jt) {
            f32x4 acc = {};
            acc = __builtin_amdgcn_mfma_f32_16x16x32_bf16(Am, B1l[jt], acc, 0, 0, 0);
            acc = __builtin_amdgcn_mfma_f32_16x16x32_bf16(Ax, B1r[jt], acc, 0, 0, 0);
#pragma unroll
            for (int reg = 0; reg < 4; ++reg) {
                float h = fmaxf(acc[reg] + bias1[jt], 0.0f);
                hl[(lhi * 4 + reg) * 72 + jt * 16 + l15] = f2bf(h);
            }
        }
        bf16x8 Ah0 = *(const bf16x8*)&hl[l15 * 72 + 8 * lhi];
        bf16x8 Ah1 = *(const bf16x8*)&hl[l15 * 72 + 32 + 8 * lhi];
#pragma unroll
        for (int ct = 0; ct < 2; ++ct) {
            f32x4 acc = {};
            acc = __builtin_amdgcn_mfma_f32_16x16x32_bf16(Ah0, B2l[ct][0], acc, 0, 0, 0);
            acc = __builtin_amdgcn_mfma_f32_16x16x32_bf16(Ah1, B2l[ct][1], acc, 0, 0, 0);
            ushort* tdst = ct ? tbB : tbA;
#pragma unroll
            for (int reg = 0; reg < 4; ++reg) {
                int nr = n0 + lhi * 4 + reg;
                if (nr < N_NODES)
                    tdst[(size_t)nr * 16 + l15] = f2bf(acc[reg]);
            }
        }
#pragma unroll
        for (int ct = 0; ct < 2; ++ct) {
            f32x4 acc = {};
            acc = __builtin_amdgcn_mfma_f32_16x16x32_bf16(Ah0, B2r[ct][0], acc, 0, 0, 0);
            acc = __builtin_amdgcn_mfma_f32_16x16x32_bf16(Ah1, B2r[ct][1], acc, 0, 0, 0);
            float* rdst = ct ? rB : rA;
#pragma unroll
            for (int reg = 0; reg < 4; ++reg) {
                int nr = n0 + lhi * 4 + reg;
                if (nr < N_NODES)
                    rdst[(size_t)nr * 16 + l15] = acc[reg] + bias2[ct];
            }
        }
    }
}

// ---- launch -------------------------------------------------------------

extern "C" void kernel_launch(void* const* d_in, const int* in_sizes, int n_in,
                              void* d_out, int out_size, void* d_ws, size_t ws_size,
                              hipStream_t stream) {
    const float* x   = (const float*)d_in[0];
    const float* W1l = (const float*)d_in[1];
    const float* W1r = (const float*)d_in[2];
    const float* b1  = (const float*)d_in[3];
    const float* W2l = (const float*)d_in[4];
    const float* W2r = (const float*)d_in[5];
    const float* b2  = (const float*)d_in[6];
    const int*   ei  = (const int*)d_in[7];   // [2, N_EDGES]
    const int* src = ei;
    const int* dst = ei + N_EDGES;

    char* ws = (char*)d_ws;
    int*      gh     = (int*)ws;             ws += (size_t)NB * NBLK * 4;
    int*      btot   = (int*)ws;             ws += (size_t)(NB + 8) * 4;
    int*      bbase  = (int*)ws;             ws += (size_t)(NB + 8) * 4;
    int*      counts = (int*)ws;             ws += (size_t)N_NODES * 4;
    int*      rowptr = (int*)ws;             ws += (size_t)N_NODES * 4;
    int*      perm   = (int*)ws;             ws += (size_t)N_EDGES * 4;
    unsigned* tmp    = (unsigned*)ws;        ws += (size_t)N_EDGES * 4;
    // mbA/mbB (3.2MB each) alias tmp (6.4MB): tmp dead after count_place.
    ushort*   mbA    = (ushort*)tmp;
    ushort*   mbB    = mbA + (size_t)N_NODES * 16;
    ushort*   xbA    = (ushort*)ws;          ws += (size_t)N_NODES * 16 * 2;
    ushort*   xbB    = (ushort*)ws;          ws += (size_t)N_NODES * 16 * 2;
    ushort*   wb     = (ushort*)ws;          ws += (size_t)8192 * 2;
    ushort*   tbA    = (ushort*)ws;          ws += (size_t)N_NODES * 16 * 2;
    ushort*   tbB    = (ushort*)ws;          ws += (size_t)N_NODES * 16 * 2;
    float*    rA     = (float*)ws;           ws += (size_t)N_NODES * 16 * 4;
    float*    rB     = (float*)ws;           ws += (size_t)N_NODES * 16 * 4;

    dim3 blk(256);
    int gsgrid = (N_NODES + 127) / 128;   // 4 waves/block x 32 nodes/wave

    cast_w_kernel<<<1, blk, 0, stream>>>(W1l, W1r, W2l, W2r, wb);
    bucket_hist_kernel<<<NBLK, blk, 0, stream>>>(dst, gh, x, xbA, xbB);
    bucket_scan_kernel<<<NB, blk, 0, stream>>>(gh, btot);
    base_scan_kernel<<<1, 1, 0, stream>>>(btot, bbase);
    bucket_place_kernel<<<NBLK, blk, 0, stream>>>(src, dst, gh, bbase, tmp);
    count_place_kernel<<<NB, dim3(512), 0, stream>>>(tmp, bbase, counts, rowptr, perm);

    gather_mean_half_kernel<<<gsgrid, blk, 0, stream>>>(xbA, rowptr, counts, perm, mbA);
    gather_mean_half_kernel<<<gsgrid, blk, 0, stream>>>(xbB, rowptr, counts, perm, mbB);
    transform_mfma_kernel<<<(N_NODES + 127) / 128, blk, 0, stream>>>(
        xbA, xbB, mbA, mbB, wb, b1, b2, tbA, tbB, rA, rB);
    gather_final_half_kernel<<<gsgrid, blk, 0, stream>>>(tbA, rowptr, counts, perm,
                                                        rA, (float*)d_out, 0);
    gather_final_half_kernel<<<gsgrid, blk, 0, stream>>>(tbB, rowptr, counts, perm,
                                                        rB, (float*)d_out, 1);
}

// Round 15
// 148.992 us; speedup vs baseline: 1.8434x; 1.0869x over previous
//
#include <hip/hip_runtime.h>

#define N_NODES 100000
#define N_EDGES 1600000
#define IN_C 32
#define HID_C 64
#define OUT_C 32

#define EPB 4096                                 // edges per hist/place block
#define NBLK ((N_EDGES + EPB - 1) / EPB)         // 391
#define BSH 8                                    // 256 nodes per bucket
#define BKN (1 << BSH)
#define NB ((N_NODES + BKN - 1) / BKN)           // 391

typedef __attribute__((ext_vector_type(8))) short bf16x8;
typedef __attribute__((ext_vector_type(8))) unsigned short u16x8;
typedef __attribute__((ext_vector_type(4))) float f32x4;

__device__ __forceinline__ unsigned short f2bf(float f) {
    unsigned u = __float_as_uint(f);
    return (unsigned short)((u + 0x7fffu + ((u >> 16) & 1u)) >> 16);
}
__device__ __forceinline__ float bf2f(unsigned short h) {
    return __uint_as_float((unsigned)h << 16);
}

// ---- pass A: bucket histogram (LDS only) + fused x->bf16 split cast -----
__global__ __launch_bounds__(256) void bucket_hist_kernel(
    const int* __restrict__ dst, int* __restrict__ gh,
    const float* __restrict__ x, ushort* __restrict__ xbA,
    ushort* __restrict__ xbB) {
    // grid-stride cast: 400K 8-float groups over 391 blocks (4 iters)
    for (int ci = blockIdx.x * 256 + threadIdx.x; ci < N_NODES * IN_C / 8;
         ci += NBLK * 256) {
        int n = ci >> 2;
        int oc = ci & 3;
        const float4* p = (const float4*)&x[(size_t)ci * 8];
        float4 a = p[0], b = p[1];
        u16x8 o;
        o[0] = f2bf(a.x); o[1] = f2bf(a.y); o[2] = f2bf(a.z); o[3] = f2bf(a.w);
        o[4] = f2bf(b.x); o[5] = f2bf(b.y); o[6] = f2bf(b.z); o[7] = f2bf(b.w);
        ushort* dstp = (oc < 2) ? xbA : xbB;
        *(u16x8*)&dstp[(size_t)n * 16 + (oc & 1) * 8] = o;
    }

    __shared__ int lh[NB];
    for (int i = threadIdx.x; i < NB; i += 256) lh[i] = 0;
    __syncthreads();
    int base = blockIdx.x * EPB;
#pragma unroll
    for (int j = 0; j < EPB / 256; ++j) {
        int e = base + j * 256 + threadIdx.x;
        if (e < N_EDGES) atomicAdd(&lh[dst[e] >> BSH], 1);
    }
    __syncthreads();
    for (int i = threadIdx.x; i < NB; i += 256)
        gh[i * NBLK + blockIdx.x] = lh[i];
}

__global__ void cast_w_kernel(const float* __restrict__ w1l,
                              const float* __restrict__ w1r,
                              const float* __restrict__ w2l,
                              const float* __restrict__ w2r,
                              ushort* __restrict__ wb) {
    for (int i = threadIdx.x; i < 8192; i += 256) {
        float v;
        if (i < 2048) v = w1l[i];
        else if (i < 4096) v = w1r[i - 2048];
        else if (i < 6144) v = w2l[i - 4096];
        else v = w2r[i - 6144];
        wb[i] = f2bf(v);
    }
}

// ---- pass B: per-bucket exclusive scan of gh across blocks + totals -----
// NBLK=391 entries per bucket: 2 per thread.
__global__ __launch_bounds__(256) void bucket_scan_kernel(
    int* __restrict__ gh, int* __restrict__ btot) {
    int b = blockIdx.x;
    int t = threadIdx.x;
    __shared__ int ssum[256];
    int base = t * 2;
    int v0 = (base < NBLK) ? gh[b * NBLK + base] : 0;
    int v1 = (base + 1 < NBLK) ? gh[b * NBLK + base + 1] : 0;
    int s = v0 + v1;
    ssum[t] = s;
    __syncthreads();
    for (int o = 1; o < 256; o <<= 1) {
        int val = (t >= o) ? ssum[t - o] : 0;
        __syncthreads();
        ssum[t] += val;
        __syncthreads();
    }
    int texcl = ssum[t] - s;
    if (base < NBLK) gh[b * NBLK + base] = texcl;
    if (base + 1 < NBLK) gh[b * NBLK + base + 1] = texcl + v0;
    if (t == 255) btot[b] = ssum[255];
}

// ---- pass C: parallel scan of bucket totals -> bucket bases -------------
__global__ __launch_bounds__(512) void base_scan_kernel(
    const int* __restrict__ btot, int* __restrict__ bbase) {
    __shared__ int s[512];
    int t = threadIdx.x;
    int v = (t < NB) ? btot[t] : 0;
    s[t] = v;
    __syncthreads();
    for (int o = 1; o < 512; o <<= 1) {
        int u = (t >= o) ? s[t - o] : 0;
        __syncthreads();
        s[t] += u;
        __syncthreads();
    }
    if (t < NB) bbase[t] = s[t] - v;
    if (t == NB - 1) bbase[NB] = s[t];
}

// ---- pass D: place packed (src<<8 | dst&255) into bucket-sorted tmp -----
// EPB=4096 -> ~10.5 edges per (block,bucket) run (~42B) vs 2.6 at EPB=1024:
// write line amplification ~6x -> ~2.3x.
__global__ __launch_bounds__(256) void bucket_place_kernel(
    const int* __restrict__ src, const int* __restrict__ dst,
    const int* __restrict__ gh, const int* __restrict__ bbase,
    unsigned* __restrict__ tmp) {
    __shared__ int cur[NB];
    for (int i = threadIdx.x; i < NB; i += 256)
        cur[i] = bbase[i] + gh[i * NBLK + blockIdx.x];
    __syncthreads();
    int base = blockIdx.x * EPB;
#pragma unroll
    for (int j = 0; j < EPB / 256; ++j) {
        int e = base + j * 256 + threadIdx.x;
        if (e < N_EDGES) {
            int d = dst[e];
            int slot = atomicAdd(&cur[d >> BSH], 1);
            tmp[slot] = ((unsigned)src[e] << 8) | (unsigned)(d & (BKN - 1));
        }
    }
}

// ---- pass E: per-bucket counts + rowptr + perm (all LDS) ----------------
__global__ __launch_bounds__(512) void count_place_kernel(
    const unsigned* __restrict__ tmp, const int* __restrict__ bbase,
    int* __restrict__ counts, int* __restrict__ rowptr,
    int* __restrict__ perm) {
    __shared__ int lcnt[BKN];
    __shared__ int sscan[BKN];
    __shared__ int cur[BKN];
    int b = blockIdx.x;
    int tid = threadIdx.x;
    int start = bbase[b], end = bbase[b + 1];
    if (tid < BKN) lcnt[tid] = 0;
    __syncthreads();
    for (int i = start + tid; i < end; i += 512)
        atomicAdd(&lcnt[tmp[i] & (BKN - 1)], 1);
    __syncthreads();
    if (tid < BKN) sscan[tid] = lcnt[tid];
    __syncthreads();
    for (int o = 1; o < BKN; o <<= 1) {
        int v = 0;
        if (tid < BKN && tid >= o) v = sscan[tid - o];
        __syncthreads();
        if (tid < BKN) sscan[tid] += v;
        __syncthreads();
    }
    if (tid < BKN) {
        int excl = sscan[tid] - lcnt[tid] + start;
        cur[tid] = excl;
        int n = (b << BSH) + tid;
        if (n < N_NODES) { rowptr[n] = excl; counts[n] = lcnt[tid]; }
    }
    __syncthreads();
    for (int i = start + tid; i < end; i += 512) {
        unsigned p = tmp[i];
        int slot = atomicAdd(&cur[p & (BKN - 1)], 1);
        perm[slot] = (int)(p >> 8);
    }
}

#define GSG ((N_NODES + 127) / 128)   // 782 blocks per half

// ---- serial-per-lane gather-mean, BOTH halves in one launch -------------
// blockIdx < GSG -> half A, else half B (disjoint tables, no shared lines).
// Lane owns (node, 8-ch octet); no cross-lane ops; edge loop chunked by 4.
__global__ __launch_bounds__(256) void gather_mean_kernel(
    const ushort* __restrict__ xbA, const ushort* __restrict__ xbB,
    const int* __restrict__ rowptr, const int* __restrict__ counts,
    const int* __restrict__ perm, ushort* __restrict__ mbA,
    ushort* __restrict__ mbB) {
    int half = blockIdx.x >= GSG;
    int blk = blockIdx.x - half * GSG;
    const ushort* xh = half ? xbB : xbA;
    ushort* mh = half ? mbB : mbA;
    int lane = threadIdx.x & 63;
    int wid = threadIdx.x >> 6;
    int n = (blk * 4 + wid) * 32 + (lane >> 1);
    int q = lane & 1;
    if (n >= N_NODES) return;
    int st = rowptr[n];
    int cn = counts[n];

    float acc[8] = {0, 0, 0, 0, 0, 0, 0, 0};
    int i = 0;
    for (; i + 4 <= cn; i += 4) {
        int p0 = perm[st + i + 0];
        int p1 = perm[st + i + 1];
        int p2 = perm[st + i + 2];
        int p3 = perm[st + i + 3];
        u16x8 v0 = *(const u16x8*)&xh[(size_t)p0 * 16 + q * 8];
        u16x8 v1 = *(const u16x8*)&xh[(size_t)p1 * 16 + q * 8];
        u16x8 v2 = *(const u16x8*)&xh[(size_t)p2 * 16 + q * 8];
        u16x8 v3 = *(const u16x8*)&xh[(size_t)p3 * 16 + q * 8];
#pragma unroll
        for (int j = 0; j < 8; ++j)
            acc[j] += (bf2f(v0[j]) + bf2f(v1[j])) + (bf2f(v2[j]) + bf2f(v3[j]));
    }
    for (; i < cn; ++i) {
        int p = perm[st + i];
        u16x8 v = *(const u16x8*)&xh[(size_t)p * 16 + q * 8];
#pragma unroll
        for (int j = 0; j < 8; ++j) acc[j] += bf2f(v[j]);
    }

    float inv = 1.0f / fmaxf((float)cn, 1.0f);
    u16x8 o;
#pragma unroll
    for (int j = 0; j < 8; ++j) o[j] = f2bf(acc[j] * inv);
    *(u16x8*)&mh[(size_t)n * 16 + q * 8] = o;
}

// ---- serial-per-lane gather-final, BOTH halves in one launch ------------
__global__ __launch_bounds__(256) void gather_final_kernel(
    const ushort* __restrict__ tbA, const ushort* __restrict__ tbB,
    const int* __restrict__ rowptr, const int* __restrict__ counts,
    const int* __restrict__ perm, const float* __restrict__ rA,
    const float* __restrict__ rB, float* __restrict__ out) {
    int half = blockIdx.x >= GSG;
    int blk = blockIdx.x - half * GSG;
    const ushort* th = half ? tbB : tbA;
    const float* rh = half ? rB : rA;
    int lane = threadIdx.x & 63;
    int wid = threadIdx.x >> 6;
    int n = (blk * 4 + wid) * 32 + (lane >> 1);
    int q = lane & 1;
    if (n >= N_NODES) return;
    int st = rowptr[n];
    int cn = counts[n];

    float acc[8] = {0, 0, 0, 0, 0, 0, 0, 0};
    int i = 0;
    for (; i + 4 <= cn; i += 4) {
        int p0 = perm[st + i + 0];
        int p1 = perm[st + i + 1];
        int p2 = perm[st + i + 2];
        int p3 = perm[st + i + 3];
        u16x8 v0 = *(const u16x8*)&th[(size_t)p0 * 16 + q * 8];
        u16x8 v1 = *(const u16x8*)&th[(size_t)p1 * 16 + q * 8];
        u16x8 v2 = *(const u16x8*)&th[(size_t)p2 * 16 + q * 8];
        u16x8 v3 = *(const u16x8*)&th[(size_t)p3 * 16 + q * 8];
#pragma unroll
        for (int j = 0; j < 8; ++j)
            acc[j] += (bf2f(v0[j]) + bf2f(v1[j])) + (bf2f(v2[j]) + bf2f(v3[j]));
    }
    for (; i < cn; ++i) {
        int p = perm[st + i];
        u16x8 v = *(const u16x8*)&th[(size_t)p * 16 + q * 8];
#pragma unroll
        for (int j = 0; j < 8; ++j) acc[j] += bf2f(v[j]);
    }

    float inv = 1.0f / fmaxf((float)cn, 1.0f);
    const float4* rp = (const float4*)&rh[(size_t)n * 16 + q * 8];
    float4 r0 = rp[0], r1 = rp[1];
    float4* op = (float4*)&out[(size_t)n * 32 + half * 16 + q * 8];
    op[0] = make_float4(acc[0] * inv + r0.x, acc[1] * inv + r0.y,
                        acc[2] * inv + r0.z, acc[3] * inv + r0.w);
    op[1] = make_float4(acc[4] * inv + r1.x, acc[5] * inv + r1.y,
                        acc[6] * inv + r1.z, acc[7] * inv + r1.w);
}

// ---- MFMA transform: reads/writes split half-tables ---------------------
__global__ __launch_bounds__(256) void transform_mfma_kernel(
    const ushort* __restrict__ xbA, const ushort* __restrict__ xbB,
    const ushort* __restrict__ mbA, const ushort* __restrict__ mbB,
    const ushort* __restrict__ wb, const float* __restrict__ b1,
    const float* __restrict__ b2, ushort* __restrict__ tbA,
    ushort* __restrict__ tbB, float* __restrict__ rA,
    float* __restrict__ rB) {
    __shared__ ushort hlds[4][16 * 72];
    int lane = threadIdx.x & 63;
    int wid = threadIdx.x >> 6;
    int l15 = lane & 15, lhi = lane >> 4;

    const ushort* w1l = wb;
    const ushort* w1r = wb + 2048;
    const ushort* w2l = wb + 4096;
    const ushort* w2r = wb + 6144;

    bf16x8 B1l[4], B1r[4];
#pragma unroll
    for (int jt = 0; jt < 4; ++jt) {
        B1l[jt] = *(const bf16x8*)&w1l[(jt * 16 + l15) * 32 + 8 * lhi];
        B1r[jt] = *(const bf16x8*)&w1r[(jt * 16 + l15) * 32 + 8 * lhi];
    }
    bf16x8 B2l[2][2], B2r[2][2];
#pragma unroll
    for (int ct = 0; ct < 2; ++ct)
#pragma unroll
        for (int kc = 0; kc < 2; ++kc) {
            B2l[ct][kc] = *(const bf16x8*)&w2l[(ct * 16 + l15) * 64 + kc * 32 + 8 * lhi];
            B2r[ct][kc] = *(const bf16x8*)&w2r[(ct * 16 + l15) * 64 + kc * 32 + 8 * lhi];
        }
    float bias1[4];
#pragma unroll
    for (int jt = 0; jt < 4; ++jt) bias1[jt] = b1[jt * 16 + l15];
    float bias2[2] = { b2[l15], b2[16 + l15] };

    ushort* hl = hlds[wid];

#pragma unroll
    for (int chunk = 0; chunk < 2; ++chunk) {
        int n0 = blockIdx.x * 128 + wid * 32 + chunk * 16;
        int nrow = n0 + l15;
        bf16x8 Am = {}, Ax = {};
        if (nrow < N_NODES) {
            const ushort* ms = (lhi < 2) ? mbA : mbB;
            const ushort* xs = (lhi < 2) ? xbA : xbB;
            Am = *(const bf16x8*)&ms[(size_t)nrow * 16 + 8 * (lhi & 1)];
            Ax = *(const bf16x8*)&xs[(size_t)nrow * 16 + 8 * (lhi & 1)];
        }
#pragma unroll
        for (int jt = 0; jt < 4; ++jt) {
            f32x4 acc = {};
            acc = __builtin_amdgcn_mfma_f32_16x16x32_bf16(Am, B1l[jt], acc, 0, 0, 0);
            acc = __builtin_amdgcn_mfma_f32_16x16x32_bf16(Ax, B1r[jt], acc, 0, 0, 0);
#pragma unroll
            for (int reg = 0; reg < 4; ++reg) {
                float h = fmaxf(acc[reg] + bias1[jt], 0.0f);
                hl[(lhi * 4 + reg) * 72 + jt * 16 + l15] = f2bf(h);
            }
        }
        bf16x8 Ah0 = *(const bf16x8*)&hl[l15 * 72 + 8 * lhi];
        bf16x8 Ah1 = *(const bf16x8*)&hl[l15 * 72 + 32 + 8 * lhi];
#pragma unroll
        for (int ct = 0; ct < 2; ++ct) {
            f32x4 acc = {};
            acc = __builtin_amdgcn_mfma_f32_16x16x32_bf16(Ah0, B2l[ct][0], acc, 0, 0, 0);
            acc = __builtin_amdgcn_mfma_f32_16x16x32_bf16(Ah1, B2l[ct][1], acc, 0, 0, 0);
            ushort* tdst = ct ? tbB : tbA;
#pragma unroll
            for (int reg = 0; reg < 4; ++reg) {
                int nr = n0 + lhi * 4 + reg;
                if (nr < N_NODES)
                    tdst[(size_t)nr * 16 + l15] = f2bf(acc[reg]);
            }
        }
#pragma unroll
        for (int ct = 0; ct < 2; ++ct) {
            f32x4 acc = {};
            acc = __builtin_amdgcn_mfma_f32_16x16x32_bf16(Ah0, B2r[ct][0], acc, 0, 0, 0);
            acc = __builtin_amdgcn_mfma_f32_16x16x32_bf16(Ah1, B2r[ct][1], acc, 0, 0, 0);
            float* rdst = ct ? rB : rA;
#pragma unroll
            for (int reg = 0; reg < 4; ++reg) {
                int nr = n0 + lhi * 4 + reg;
                if (nr < N_NODES)
                    rdst[(size_t)nr * 16 + l15] = acc[reg] + bias2[ct];
            }
        }
    }
}

// ---- launch -------------------------------------------------------------

extern "C" void kernel_launch(void* const* d_in, const int* in_sizes, int n_in,
                              void* d_out, int out_size, void* d_ws, size_t ws_size,
                              hipStream_t stream) {
    const float* x   = (const float*)d_in[0];
    const float* W1l = (const float*)d_in[1];
    const float* W1r = (const float*)d_in[2];
    const float* b1  = (const float*)d_in[3];
    const float* W2l = (const float*)d_in[4];
    const float* W2r = (const float*)d_in[5];
    const float* b2  = (const float*)d_in[6];
    const int*   ei  = (const int*)d_in[7];   // [2, N_EDGES]
    const int* src = ei;
    const int* dst = ei + N_EDGES;

    char* ws = (char*)d_ws;
    int*      gh     = (int*)ws;             ws += (size_t)NB * NBLK * 4;
    int*      btot   = (int*)ws;             ws += (size_t)(NB + 8) * 4;
    int*      bbase  = (int*)ws;             ws += (size_t)(NB + 8) * 4;
    int*      counts = (int*)ws;             ws += (size_t)N_NODES * 4;
    int*      rowptr = (int*)ws;             ws += (size_t)N_NODES * 4;
    int*      perm   = (int*)ws;             ws += (size_t)N_EDGES * 4;
    unsigned* tmp    = (unsigned*)ws;        ws += (size_t)N_EDGES * 4;
    // mbA/mbB (3.2MB each) alias tmp (6.4MB): tmp dead after count_place.
    ushort*   mbA    = (ushort*)tmp;
    ushort*   mbB    = mbA + (size_t)N_NODES * 16;
    ushort*   xbA    = (ushort*)ws;          ws += (size_t)N_NODES * 16 * 2;
    ushort*   xbB    = (ushort*)ws;          ws += (size_t)N_NODES * 16 * 2;
    ushort*   wb     = (ushort*)ws;          ws += (size_t)8192 * 2;
    ushort*   tbA    = (ushort*)ws;          ws += (size_t)N_NODES * 16 * 2;
    ushort*   tbB    = (ushort*)ws;          ws += (size_t)N_NODES * 16 * 2;
    float*    rA     = (float*)ws;           ws += (size_t)N_NODES * 16 * 4;
    float*    rB     = (float*)ws;           ws += (size_t)N_NODES * 16 * 4;

    dim3 blk(256);

    cast_w_kernel<<<1, blk, 0, stream>>>(W1l, W1r, W2l, W2r, wb);
    bucket_hist_kernel<<<NBLK, blk, 0, stream>>>(dst, gh, x, xbA, xbB);
    bucket_scan_kernel<<<NB, blk, 0, stream>>>(gh, btot);
    base_scan_kernel<<<1, dim3(512), 0, stream>>>(btot, bbase);
    bucket_place_kernel<<<NBLK, blk, 0, stream>>>(src, dst, gh, bbase, tmp);
    count_place_kernel<<<NB, dim3(512), 0, stream>>>(tmp, bbase, counts, rowptr, perm);

    gather_mean_kernel<<<2 * GSG, blk, 0, stream>>>(xbA, xbB, rowptr, counts,
                                                    perm, mbA, mbB);
    transform_mfma_kernel<<<(N_NODES + 127) / 128, blk, 0, stream>>>(
        xbA, xbB, mbA, mbB, wb, b1, b2, tbA, tbB, rA, rB);
    gather_final_kernel<<<2 * GSG, blk, 0, stream>>>(tbA, tbB, rowptr, counts,
                                                     perm, rA, rB, (float*)d_out);
}

// Round 16
// 136.051 us; speedup vs baseline: 2.0187x; 1.0951x over previous
//
#include <hip/hip_runtime.h>

#define N_NODES 100000
#define N_EDGES 1600000
#define IN_C 32
#define HID_C 64
#define OUT_C 32

#define EPB 4096                                 // edges per hist/place block
#define NBLK ((N_EDGES + EPB - 1) / EPB)         // 391
#define BSH 8                                    // 256 nodes per bucket
#define BKN (1 << BSH)
#define NB ((N_NODES + BKN - 1) / BKN)           // 391

typedef __attribute__((ext_vector_type(8))) short bf16x8;
typedef __attribute__((ext_vector_type(8))) unsigned short u16x8;
typedef __attribute__((ext_vector_type(4))) float f32x4;

__device__ __forceinline__ unsigned short f2bf(float f) {
    unsigned u = __float_as_uint(f);
    return (unsigned short)((u + 0x7fffu + ((u >> 16) & 1u)) >> 16);
}
__device__ __forceinline__ float bf2f(unsigned short h) {
    return __uint_as_float((unsigned)h << 16);
}

// ---- pass A: bucket histogram (LDS only) + fused x->bf16 split cast -----
__global__ __launch_bounds__(256) void bucket_hist_kernel(
    const int* __restrict__ dst, int* __restrict__ gh,
    const float* __restrict__ x, ushort* __restrict__ xbA,
    ushort* __restrict__ xbB) {
    for (int ci = blockIdx.x * 256 + threadIdx.x; ci < N_NODES * IN_C / 8;
         ci += NBLK * 256) {
        int n = ci >> 2;
        int oc = ci & 3;
        const float4* p = (const float4*)&x[(size_t)ci * 8];
        float4 a = p[0], b = p[1];
        u16x8 o;
        o[0] = f2bf(a.x); o[1] = f2bf(a.y); o[2] = f2bf(a.z); o[3] = f2bf(a.w);
        o[4] = f2bf(b.x); o[5] = f2bf(b.y); o[6] = f2bf(b.z); o[7] = f2bf(b.w);
        ushort* dstp = (oc < 2) ? xbA : xbB;
        *(u16x8*)&dstp[(size_t)n * 16 + (oc & 1) * 8] = o;
    }

    __shared__ int lh[NB];
    for (int i = threadIdx.x; i < NB; i += 256) lh[i] = 0;
    __syncthreads();
    int base = blockIdx.x * EPB;
#pragma unroll
    for (int j = 0; j < EPB / 256; ++j) {
        int e = base + j * 256 + threadIdx.x;
        if (e < N_EDGES) atomicAdd(&lh[dst[e] >> BSH], 1);
    }
    __syncthreads();
    for (int i = threadIdx.x; i < NB; i += 256)
        gh[i * NBLK + blockIdx.x] = lh[i];
}

__global__ void cast_w_kernel(const float* __restrict__ w1l,
                              const float* __restrict__ w1r,
                              const float* __restrict__ w2l,
                              const float* __restrict__ w2r,
                              ushort* __restrict__ wb) {
    for (int i = threadIdx.x; i < 8192; i += 256) {
        float v;
        if (i < 2048) v = w1l[i];
        else if (i < 4096) v = w1r[i - 2048];
        else if (i < 6144) v = w2l[i - 4096];
        else v = w2r[i - 6144];
        wb[i] = f2bf(v);
    }
}

// ---- pass B: per-bucket exclusive scan of gh across blocks + totals -----
__global__ __launch_bounds__(256) void bucket_scan_kernel(
    int* __restrict__ gh, int* __restrict__ btot) {
    int b = blockIdx.x;
    int t = threadIdx.x;
    __shared__ int ssum[256];
    int base = t * 2;
    int v0 = (base < NBLK) ? gh[b * NBLK + base] : 0;
    int v1 = (base + 1 < NBLK) ? gh[b * NBLK + base + 1] : 0;
    int s = v0 + v1;
    ssum[t] = s;
    __syncthreads();
    for (int o = 1; o < 256; o <<= 1) {
        int val = (t >= o) ? ssum[t - o] : 0;
        __syncthreads();
        ssum[t] += val;
        __syncthreads();
    }
    int texcl = ssum[t] - s;
    if (base < NBLK) gh[b * NBLK + base] = texcl;
    if (base + 1 < NBLK) gh[b * NBLK + base + 1] = texcl + v0;
    if (t == 255) btot[b] = ssum[255];
}

// ---- pass C: parallel scan of bucket totals -> bucket bases -------------
__global__ __launch_bounds__(512) void base_scan_kernel(
    const int* __restrict__ btot, int* __restrict__ bbase) {
    __shared__ int s[512];
    int t = threadIdx.x;
    int v = (t < NB) ? btot[t] : 0;
    s[t] = v;
    __syncthreads();
    for (int o = 1; o < 512; o <<= 1) {
        int u = (t >= o) ? s[t - o] : 0;
        __syncthreads();
        s[t] += u;
        __syncthreads();
    }
    if (t < NB) bbase[t] = s[t] - v;
    if (t == NB - 1) bbase[NB] = s[t];
}

// ---- pass D: place packed (src<<8 | dst&255) into bucket-sorted tmp -----
__global__ __launch_bounds__(256) void bucket_place_kernel(
    const int* __restrict__ src, const int* __restrict__ dst,
    const int* __restrict__ gh, const int* __restrict__ bbase,
    unsigned* __restrict__ tmp) {
    __shared__ int cur[NB];
    for (int i = threadIdx.x; i < NB; i += 256)
        cur[i] = bbase[i] + gh[i * NBLK + blockIdx.x];
    __syncthreads();
    int base = blockIdx.x * EPB;
#pragma unroll
    for (int j = 0; j < EPB / 256; ++j) {
        int e = base + j * 256 + threadIdx.x;
        if (e < N_EDGES) {
            int d = dst[e];
            int slot = atomicAdd(&cur[d >> BSH], 1);
            tmp[slot] = ((unsigned)src[e] << 8) | (unsigned)(d & (BKN - 1));
        }
    }
}

// ---- pass E: per-bucket counts + rowptr + perm (all LDS) ----------------
__global__ __launch_bounds__(512) void count_place_kernel(
    const unsigned* __restrict__ tmp, const int* __restrict__ bbase,
    int* __restrict__ counts, int* __restrict__ rowptr,
    int* __restrict__ perm) {
    __shared__ int lcnt[BKN];
    __shared__ int sscan[BKN];
    __shared__ int cur[BKN];
    int b = blockIdx.x;
    int tid = threadIdx.x;
    int start = bbase[b], end = bbase[b + 1];
    if (tid < BKN) lcnt[tid] = 0;
    __syncthreads();
    for (int i = start + tid; i < end; i += 512)
        atomicAdd(&lcnt[tmp[i] & (BKN - 1)], 1);
    __syncthreads();
    if (tid < BKN) sscan[tid] = lcnt[tid];
    __syncthreads();
    for (int o = 1; o < BKN; o <<= 1) {
        int v = 0;
        if (tid < BKN && tid >= o) v = sscan[tid - o];
        __syncthreads();
        if (tid < BKN) sscan[tid] += v;
        __syncthreads();
    }
    if (tid < BKN) {
        int excl = sscan[tid] - lcnt[tid] + start;
        cur[tid] = excl;
        int n = (b << BSH) + tid;
        if (n < N_NODES) { rowptr[n] = excl; counts[n] = lcnt[tid]; }
    }
    __syncthreads();
    for (int i = start + tid; i < end; i += 512) {
        unsigned p = tmp[i];
        int slot = atomicAdd(&cur[p & (BKN - 1)], 1);
        perm[slot] = (int)(p >> 8);
    }
}

// 784 blocks per half, 128 nodes/block; grid = 1568 (multiple of 8).
// XCD partition: blockIdx%8 in {0..3} -> half A, {4..7} -> half B, so each
// XCD's 4MB L2 only holds ONE 3.2MB half-table (L2-resident random reads)
// while both halves run concurrently at full TLP.
#define GSG8 784

// ---- serial-per-lane gather-mean, XCD-partitioned halves ----------------
__global__ __launch_bounds__(256) void gather_mean_kernel(
    const ushort* __restrict__ xbA, const ushort* __restrict__ xbB,
    const int* __restrict__ rowptr, const int* __restrict__ counts,
    const int* __restrict__ perm, ushort* __restrict__ mbA,
    ushort* __restrict__ mbB) {
    int g = blockIdx.x;
    int xcd = g & 7;
    int half = xcd >> 2;
    int sub = ((g >> 3) << 2) | (xcd & 3);       // 0..783 per half
    const ushort* xh = half ? xbB : xbA;
    ushort* mh = half ? mbB : mbA;
    int lane = threadIdx.x & 63;
    int wid = threadIdx.x >> 6;
    int n = (sub * 4 + wid) * 32 + (lane >> 1);
    int q = lane & 1;
    if (n >= N_NODES) return;
    int st = rowptr[n];
    int cn = counts[n];

    float acc[8] = {0, 0, 0, 0, 0, 0, 0, 0};
    int i = 0;
    for (; i + 4 <= cn; i += 4) {
        int p0 = perm[st + i + 0];
        int p1 = perm[st + i + 1];
        int p2 = perm[st + i + 2];
        int p3 = perm[st + i + 3];
        u16x8 v0 = *(const u16x8*)&xh[(size_t)p0 * 16 + q * 8];
        u16x8 v1 = *(const u16x8*)&xh[(size_t)p1 * 16 + q * 8];
        u16x8 v2 = *(const u16x8*)&xh[(size_t)p2 * 16 + q * 8];
        u16x8 v3 = *(const u16x8*)&xh[(size_t)p3 * 16 + q * 8];
#pragma unroll
        for (int j = 0; j < 8; ++j)
            acc[j] += (bf2f(v0[j]) + bf2f(v1[j])) + (bf2f(v2[j]) + bf2f(v3[j]));
    }
    for (; i < cn; ++i) {
        int p = perm[st + i];
        u16x8 v = *(const u16x8*)&xh[(size_t)p * 16 + q * 8];
#pragma unroll
        for (int j = 0; j < 8; ++j) acc[j] += bf2f(v[j]);
    }

    float inv = 1.0f / fmaxf((float)cn, 1.0f);
    u16x8 o;
#pragma unroll
    for (int j = 0; j < 8; ++j) o[j] = f2bf(acc[j] * inv);
    *(u16x8*)&mh[(size_t)n * 16 + q * 8] = o;
}

// ---- serial-per-lane gather-final, XCD-partitioned halves ---------------
__global__ __launch_bounds__(256) void gather_final_kernel(
    const ushort* __restrict__ tbA, const ushort* __restrict__ tbB,
    const int* __restrict__ rowptr, const int* __restrict__ counts,
    const int* __restrict__ perm, const float* __restrict__ rA,
    const float* __restrict__ rB, float* __restrict__ out) {
    int g = blockIdx.x;
    int xcd = g & 7;
    int half = xcd >> 2;
    int sub = ((g >> 3) << 2) | (xcd & 3);
    const ushort* th = half ? tbB : tbA;
    const float* rh = half ? rB : rA;
    int lane = threadIdx.x & 63;
    int wid = threadIdx.x >> 6;
    int n = (sub * 4 + wid) * 32 + (lane >> 1);
    int q = lane & 1;
    if (n >= N_NODES) return;
    int st = rowptr[n];
    int cn = counts[n];

    float acc[8] = {0, 0, 0, 0, 0, 0, 0, 0};
    int i = 0;
    for (; i + 4 <= cn; i += 4) {
        int p0 = perm[st + i + 0];
        int p1 = perm[st + i + 1];
        int p2 = perm[st + i + 2];
        int p3 = perm[st + i + 3];
        u16x8 v0 = *(const u16x8*)&th[(size_t)p0 * 16 + q * 8];
        u16x8 v1 = *(const u16x8*)&th[(size_t)p1 * 16 + q * 8];
        u16x8 v2 = *(const u16x8*)&th[(size_t)p2 * 16 + q * 8];
        u16x8 v3 = *(const u16x8*)&th[(size_t)p3 * 16 + q * 8];
#pragma unroll
        for (int j = 0; j < 8; ++j)
            acc[j] += (bf2f(v0[j]) + bf2f(v1[j])) + (bf2f(v2[j]) + bf2f(v3[j]));
    }
    for (; i < cn; ++i) {
        int p = perm[st + i];
        u16x8 v = *(const u16x8*)&th[(size_t)p * 16 + q * 8];
#pragma unroll
        for (int j = 0; j < 8; ++j) acc[j] += bf2f(v[j]);
    }

    float inv = 1.0f / fmaxf((float)cn, 1.0f);
    const float4* rp = (const float4*)&rh[(size_t)n * 16 + q * 8];
    float4 r0 = rp[0], r1 = rp[1];
    float4* op = (float4*)&out[(size_t)n * 32 + half * 16 + q * 8];
    op[0] = make_float4(acc[0] * inv + r0.x, acc[1] * inv + r0.y,
                        acc[2] * inv + r0.z, acc[3] * inv + r0.w);
    op[1] = make_float4(acc[4] * inv + r1.x, acc[5] * inv + r1.y,
                        acc[6] * inv + r1.z, acc[7] * inv + r1.w);
}

// ---- MFMA transform: reads/writes split half-tables ---------------------
__global__ __launch_bounds__(256) void transform_mfma_kernel(
    const ushort* __restrict__ xbA, const ushort* __restrict__ xbB,
    const ushort* __restrict__ mbA, const ushort* __restrict__ mbB,
    const ushort* __restrict__ wb, const float* __restrict__ b1,
    const float* __restrict__ b2, ushort* __restrict__ tbA,
    ushort* __restrict__ tbB, float* __restrict__ rA,
    float* __restrict__ rB) {
    __shared__ ushort hlds[4][16 * 72];
    int lane = threadIdx.x & 63;
    int wid = threadIdx.x >> 6;
    int l15 = lane & 15, lhi = lane >> 4;

    const ushort* w1l = wb;
    const ushort* w1r = wb + 2048;
    const ushort* w2l = wb + 4096;
    const ushort* w2r = wb + 6144;

    bf16x8 B1l[4], B1r[4];
#pragma unroll
    for (int jt = 0; jt < 4; ++jt) {
        B1l[jt] = *(const bf16x8*)&w1l[(jt * 16 + l15) * 32 + 8 * lhi];
        B1r[jt] = *(const bf16x8*)&w1r[(jt * 16 + l15) * 32 + 8 * lhi];
    }
    bf16x8 B2l[2][2], B2r[2][2];
#pragma unroll
    for (int ct = 0; ct < 2; ++ct)
#pragma unroll
        for (int kc = 0; kc < 2; ++kc) {
            B2l[ct][kc] = *(const bf16x8*)&w2l[(ct * 16 + l15) * 64 + kc * 32 + 8 * lhi];
            B2r[ct][kc] = *(const bf16x8*)&w2r[(ct * 16 + l15) * 64 + kc * 32 + 8 * lhi];
        }
    float bias1[4];
#pragma unroll
    for (int jt = 0; jt < 4; ++jt) bias1[jt] = b1[jt * 16 + l15];
    float bias2[2] = { b2[l15], b2[16 + l15] };

    ushort* hl = hlds[wid];

#pragma unroll
    for (int chunk = 0; chunk < 2; ++chunk) {
        int n0 = blockIdx.x * 128 + wid * 32 + chunk * 16;
        int nrow = n0 + l15;
        bf16x8 Am = {}, Ax = {};
        if (nrow < N_NODES) {
            const ushort* ms = (lhi < 2) ? mbA : mbB;
            const ushort* xs = (lhi < 2) ? xbA : xbB;
            Am = *(const bf16x8*)&ms[(size_t)nrow * 16 + 8 * (lhi & 1)];
            Ax = *(const bf16x8*)&xs[(size_t)nrow * 16 + 8 * (lhi & 1)];
        }
#pragma unroll
        for (int jt = 0; jt < 4; ++jt) {
            f32x4 acc = {};
            acc = __builtin_amdgcn_mfma_f32_16x16x32_bf16(Am, B1l[jt], acc, 0, 0, 0);
            acc = __builtin_amdgcn_mfma_f32_16x16x32_bf16(Ax, B1r[jt], acc, 0, 0, 0);
#pragma unroll
            for (int reg = 0; reg < 4; ++reg) {
                float h = fmaxf(acc[reg] + bias1[jt], 0.0f);
                hl[(lhi * 4 + reg) * 72 + jt * 16 + l15] = f2bf(h);
            }
        }
        bf16x8 Ah0 = *(const bf16x8*)&hl[l15 * 72 + 8 * lhi];
        bf16x8 Ah1 = *(const bf16x8*)&hl[l15 * 72 + 32 + 8 * lhi];
#pragma unroll
        for (int ct = 0; ct < 2; ++ct) {
            f32x4 acc = {};
            acc = __builtin_amdgcn_mfma_f32_16x16x32_bf16(Ah0, B2l[ct][0], acc, 0, 0, 0);
            acc = __builtin_amdgcn_mfma_f32_16x16x32_bf16(Ah1, B2l[ct][1], acc, 0, 0, 0);
            ushort* tdst = ct ? tbB : tbA;
#pragma unroll
            for (int reg = 0; reg < 4; ++reg) {
                int nr = n0 + lhi * 4 + reg;
                if (nr < N_NODES)
                    tdst[(size_t)nr * 16 + l15] = f2bf(acc[reg]);
            }
        }
#pragma unroll
        for (int ct = 0; ct < 2; ++ct) {
            f32x4 acc = {};
            acc = __builtin_amdgcn_mfma_f32_16x16x32_bf16(Ah0, B2r[ct][0], acc, 0, 0, 0);
            acc = __builtin_amdgcn_mfma_f32_16x16x32_bf16(Ah1, B2r[ct][1], acc, 0, 0, 0);
            float* rdst = ct ? rB : rA;
#pragma unroll
            for (int reg = 0; reg < 4; ++reg) {
                int nr = n0 + lhi * 4 + reg;
                if (nr < N_NODES)
                    rdst[(size_t)nr * 16 + l15] = acc[reg] + bias2[ct];
            }
        }
    }
}

// ---- launch -------------------------------------------------------------

extern "C" void kernel_launch(void* const* d_in, const int* in_sizes, int n_in,
                              void* d_out, int out_size, void* d_ws, size_t ws_size,
                              hipStream_t stream) {
    const float* x   = (const float*)d_in[0];
    const float* W1l = (const float*)d_in[1];
    const float* W1r = (const float*)d_in[2];
    const float* b1  = (const float*)d_in[3];
    const float* W2l = (const float*)d_in[4];
    const float* W2r = (const float*)d_in[5];
    const float* b2  = (const float*)d_in[6];
    const int*   ei  = (const int*)d_in[7];   // [2, N_EDGES]
    const int* src = ei;
    const int* dst = ei + N_EDGES;

    char* ws = (char*)d_ws;
    int*      gh     = (int*)ws;             ws += (size_t)NB * NBLK * 4;
    int*      btot   = (int*)ws;             ws += (size_t)(NB + 8) * 4;
    int*      bbase  = (int*)ws;             ws += (size_t)(NB + 8) * 4;
    int*      counts = (int*)ws;             ws += (size_t)N_NODES * 4;
    int*      rowptr = (int*)ws;             ws += (size_t)N_NODES * 4;
    int*      perm   = (int*)ws;             ws += (size_t)N_EDGES * 4;
    unsigned* tmp    = (unsigned*)ws;        ws += (size_t)N_EDGES * 4;
    // mbA/mbB (3.2MB each) alias tmp (6.4MB): tmp dead after count_place.
    ushort*   mbA    = (ushort*)tmp;
    ushort*   mbB    = mbA + (size_t)N_NODES * 16;
    ushort*   xbA    = (ushort*)ws;          ws += (size_t)N_NODES * 16 * 2;
    ushort*   xbB    = (ushort*)ws;          ws += (size_t)N_NODES * 16 * 2;
    ushort*   wb     = (ushort*)ws;          ws += (size_t)8192 * 2;
    ushort*   tbA    = (ushort*)ws;          ws += (size_t)N_NODES * 16 * 2;
    ushort*   tbB    = (ushort*)ws;          ws += (size_t)N_NODES * 16 * 2;
    float*    rA     = (float*)ws;           ws += (size_t)N_NODES * 16 * 4;
    float*    rB     = (float*)ws;           ws += (size_t)N_NODES * 16 * 4;

    dim3 blk(256);

    cast_w_kernel<<<1, blk, 0, stream>>>(W1l, W1r, W2l, W2r, wb);
    bucket_hist_kernel<<<NBLK, blk, 0, stream>>>(dst, gh, x, xbA, xbB);
    bucket_scan_kernel<<<NB, blk, 0, stream>>>(gh, btot);
    base_scan_kernel<<<1, dim3(512), 0, stream>>>(btot, bbase);
    bucket_place_kernel<<<NBLK, blk, 0, stream>>>(src, dst, gh, bbase, tmp);
    count_place_kernel<<<NB, dim3(512), 0, stream>>>(tmp, bbase, counts, rowptr, perm);

    gather_mean_kernel<<<2 * GSG8, blk, 0, stream>>>(xbA, xbB, rowptr, counts,
                                                     perm, mbA, mbB);
    transform_mfma_kernel<<<(N_NODES + 127) / 128, blk, 0, stream>>>(
        xbA, xbB, mbA, mbB, wb, b1, b2, tbA, tbB, rA, rB);
    gather_final_kernel<<<2 * GSG8, blk, 0, stream>>>(tbA, tbB, rowptr, counts,
                                                      perm, rA, rB, (float*)d_out);
}

// Round 17
// 127.721 us; speedup vs baseline: 2.1503x; 1.0652x over previous
//
#include <hip/hip_runtime.h>

#define N_NODES 100000
#define N_EDGES 1600000
#define IN_C 32
#define HID_C 64
#define OUT_C 32

#define EPB 4096                                 // edges per place block
#define NBLK ((N_EDGES + EPB - 1) / EPB)         // 391
#define BSH 8                                    // 256 nodes per bucket
#define BKN (1 << BSH)
#define NB ((N_NODES + BKN - 1) / BKN)           // 391
#define REG 4608                                 // fixed slots per bucket (mean 4096 + 8 sigma)

typedef __attribute__((ext_vector_type(8))) short bf16x8;
typedef __attribute__((ext_vector_type(8))) unsigned short u16x8;
typedef __attribute__((ext_vector_type(4))) float f32x4;

__device__ __forceinline__ unsigned short f2bf(float f) {
    unsigned u = __float_as_uint(f);
    return (unsigned short)((u + 0x7fffu + ((u >> 16) & 1u)) >> 16);
}
__device__ __forceinline__ float bf2f(unsigned short h) {
    return __uint_as_float((unsigned)h << 16);
}

// ---- weights cast + zero bucket counters --------------------------------
__global__ void cast_w_kernel(const float* __restrict__ w1l,
                              const float* __restrict__ w1r,
                              const float* __restrict__ w2l,
                              const float* __restrict__ w2r,
                              ushort* __restrict__ wb, int* __restrict__ bcnt) {
    for (int i = threadIdx.x; i < NB; i += 256) bcnt[i] = 0;
    for (int i = threadIdx.x; i < 8192; i += 256) {
        float v;
        if (i < 2048) v = w1l[i];
        else if (i < 4096) v = w1r[i - 2048];
        else if (i < 6144) v = w2l[i - 4096];
        else v = w2r[i - 6144];
        wb[i] = f2bf(v);
    }
}

// ---- place: LDS hist -> global range reservation -> write packed pairs --
// Edges kept in registers (one read of src/dst). Fixed per-bucket regions
// (bucket b owns tmp[b*REG .. b*REG+REG)): no global prefix scan needed.
// Also fuses the x -> bf16 split-cast (grid-stride).
__global__ __launch_bounds__(256) void place_kernel(
    const int* __restrict__ src, const int* __restrict__ dst,
    const float* __restrict__ x, ushort* __restrict__ xbA,
    ushort* __restrict__ xbB, int* __restrict__ bcnt,
    unsigned* __restrict__ tmp) {
    for (int ci = blockIdx.x * 256 + threadIdx.x; ci < N_NODES * IN_C / 8;
         ci += NBLK * 256) {
        int n = ci >> 2;
        int oc = ci & 3;
        const float4* p = (const float4*)&x[(size_t)ci * 8];
        float4 a = p[0], b = p[1];
        u16x8 o;
        o[0] = f2bf(a.x); o[1] = f2bf(a.y); o[2] = f2bf(a.z); o[3] = f2bf(a.w);
        o[4] = f2bf(b.x); o[5] = f2bf(b.y); o[6] = f2bf(b.z); o[7] = f2bf(b.w);
        ushort* dstp = (oc < 2) ? xbA : xbB;
        *(u16x8*)&dstp[(size_t)n * 16 + (oc & 1) * 8] = o;
    }

    __shared__ int lh[NB];
    __shared__ int cur[NB];
    for (int i = threadIdx.x; i < NB; i += 256) lh[i] = 0;
    __syncthreads();

    int base = blockIdx.x * EPB;
    int se[16], de[16];
#pragma unroll
    for (int j = 0; j < 16; ++j) {
        int e = base + j * 256 + threadIdx.x;
        bool v = e < N_EDGES;
        se[j] = v ? src[e] : -1;
        de[j] = v ? dst[e] : 0;
        if (v) atomicAdd(&lh[de[j] >> BSH], 1);
    }
    __syncthreads();
    for (int i = threadIdx.x; i < NB; i += 256)
        cur[i] = i * REG + atomicAdd(&bcnt[i], lh[i]);
    __syncthreads();
#pragma unroll
    for (int j = 0; j < 16; ++j) {
        if (se[j] >= 0) {
            int slot = atomicAdd(&cur[de[j] >> BSH], 1);
            tmp[slot] = ((unsigned)se[j] << 8) | (unsigned)(de[j] & (BKN - 1));
        }
    }
}

// ---- count_place: per-bucket counts + rowptr + perm (one tmp read) ------
__global__ __launch_bounds__(512) void count_place_kernel(
    const unsigned* __restrict__ tmp, const int* __restrict__ bcnt,
    int* __restrict__ counts, int* __restrict__ rowptr,
    int* __restrict__ perm) {
    __shared__ int lcnt[BKN];
    __shared__ int sscan[BKN];
    __shared__ int cur[BKN];
    int b = blockIdx.x;
    int tid = threadIdx.x;
    int start = b * REG;
    int end = start + bcnt[b];

    unsigned pv[9];
    int npv = 0;
    for (int i = start + tid; i < end; i += 512) pv[npv++] = tmp[i];

    if (tid < BKN) lcnt[tid] = 0;
    __syncthreads();
    for (int k = 0; k < npv; ++k)
        atomicAdd(&lcnt[pv[k] & (BKN - 1)], 1);
    __syncthreads();
    if (tid < BKN) sscan[tid] = lcnt[tid];
    __syncthreads();
    for (int o = 1; o < BKN; o <<= 1) {
        int v = 0;
        if (tid < BKN && tid >= o) v = sscan[tid - o];
        __syncthreads();
        if (tid < BKN) sscan[tid] += v;
        __syncthreads();
    }
    if (tid < BKN) {
        int excl = sscan[tid] - lcnt[tid] + start;
        cur[tid] = excl;
        int n = (b << BSH) + tid;
        if (n < N_NODES) { rowptr[n] = excl; counts[n] = lcnt[tid]; }
    }
    __syncthreads();
    for (int k = 0; k < npv; ++k) {
        int slot = atomicAdd(&cur[pv[k] & (BKN - 1)], 1);
        perm[slot] = (int)(pv[k] >> 8);
    }
}

// 784 blocks per half, 128 nodes/block; grid = 1568 (multiple of 8).
// XCD partition: blockIdx%8 in {0..3} -> half A, {4..7} -> half B, so each
// XCD's 4MB L2 holds ONE 3.2MB half-table while both halves run at full TLP.
#define GSG8 784

// ---- serial-per-lane gather-mean, XCD-partitioned halves ----------------
__global__ __launch_bounds__(256) void gather_mean_kernel(
    const ushort* __restrict__ xbA, const ushort* __restrict__ xbB,
    const int* __restrict__ rowptr, const int* __restrict__ counts,
    const int* __restrict__ perm, ushort* __restrict__ mbA,
    ushort* __restrict__ mbB) {
    int g = blockIdx.x;
    int xcd = g & 7;
    int half = xcd >> 2;
    int sub = ((g >> 3) << 2) | (xcd & 3);       // 0..783 per half
    const ushort* xh = half ? xbB : xbA;
    ushort* mh = half ? mbB : mbA;
    int lane = threadIdx.x & 63;
    int wid = threadIdx.x >> 6;
    int n = (sub * 4 + wid) * 32 + (lane >> 1);
    int q = lane & 1;
    if (n >= N_NODES) return;
    int st = rowptr[n];
    int cn = counts[n];

    float acc[8] = {0, 0, 0, 0, 0, 0, 0, 0};
    int i = 0;
    for (; i + 4 <= cn; i += 4) {
        int p0 = perm[st + i + 0];
        int p1 = perm[st + i + 1];
        int p2 = perm[st + i + 2];
        int p3 = perm[st + i + 3];
        u16x8 v0 = *(const u16x8*)&xh[(size_t)p0 * 16 + q * 8];
        u16x8 v1 = *(const u16x8*)&xh[(size_t)p1 * 16 + q * 8];
        u16x8 v2 = *(const u16x8*)&xh[(size_t)p2 * 16 + q * 8];
        u16x8 v3 = *(const u16x8*)&xh[(size_t)p3 * 16 + q * 8];
#pragma unroll
        for (int j = 0; j < 8; ++j)
            acc[j] += (bf2f(v0[j]) + bf2f(v1[j])) + (bf2f(v2[j]) + bf2f(v3[j]));
    }
    for (; i < cn; ++i) {
        int p = perm[st + i];
        u16x8 v = *(const u16x8*)&xh[(size_t)p * 16 + q * 8];
#pragma unroll
        for (int j = 0; j < 8; ++j) acc[j] += bf2f(v[j]);
    }

    float inv = 1.0f / fmaxf((float)cn, 1.0f);
    u16x8 o;
#pragma unroll
    for (int j = 0; j < 8; ++j) o[j] = f2bf(acc[j] * inv);
    *(u16x8*)&mh[(size_t)n * 16 + q * 8] = o;
}

// ---- serial-per-lane gather-final, XCD-partitioned halves ---------------
__global__ __launch_bounds__(256) void gather_final_kernel(
    const ushort* __restrict__ tbA, const ushort* __restrict__ tbB,
    const int* __restrict__ rowptr, const int* __restrict__ counts,
    const int* __restrict__ perm, const float* __restrict__ rA,
    const float* __restrict__ rB, float* __restrict__ out) {
    int g = blockIdx.x;
    int xcd = g & 7;
    int half = xcd >> 2;
    int sub = ((g >> 3) << 2) | (xcd & 3);
    const ushort* th = half ? tbB : tbA;
    const float* rh = half ? rB : rA;
    int lane = threadIdx.x & 63;
    int wid = threadIdx.x >> 6;
    int n = (sub * 4 + wid) * 32 + (lane >> 1);
    int q = lane & 1;
    if (n >= N_NODES) return;
    int st = rowptr[n];
    int cn = counts[n];

    float acc[8] = {0, 0, 0, 0, 0, 0, 0, 0};
    int i = 0;
    for (; i + 4 <= cn; i += 4) {
        int p0 = perm[st + i + 0];
        int p1 = perm[st + i + 1];
        int p2 = perm[st + i + 2];
        int p3 = perm[st + i + 3];
        u16x8 v0 = *(const u16x8*)&th[(size_t)p0 * 16 + q * 8];
        u16x8 v1 = *(const u16x8*)&th[(size_t)p1 * 16 + q * 8];
        u16x8 v2 = *(const u16x8*)&th[(size_t)p2 * 16 + q * 8];
        u16x8 v3 = *(const u16x8*)&th[(size_t)p3 * 16 + q * 8];
#pragma unroll
        for (int j = 0; j < 8; ++j)
            acc[j] += (bf2f(v0[j]) + bf2f(v1[j])) + (bf2f(v2[j]) + bf2f(v3[j]));
    }
    for (; i < cn; ++i) {
        int p = perm[st + i];
        u16x8 v = *(const u16x8*)&th[(size_t)p * 16 + q * 8];
#pragma unroll
        for (int j = 0; j < 8; ++j) acc[j] += bf2f(v[j]);
    }

    float inv = 1.0f / fmaxf((float)cn, 1.0f);
    const float4* rp = (const float4*)&rh[(size_t)n * 16 + q * 8];
    float4 r0 = rp[0], r1 = rp[1];
    float4* op = (float4*)&out[(size_t)n * 32 + half * 16 + q * 8];
    op[0] = make_float4(acc[0] * inv + r0.x, acc[1] * inv + r0.y,
                        acc[2] * inv + r0.z, acc[3] * inv + r0.w);
    op[1] = make_float4(acc[4] * inv + r1.x, acc[5] * inv + r1.y,
                        acc[6] * inv + r1.z, acc[7] * inv + r1.w);
}

// ---- MFMA transform: reads/writes split half-tables ---------------------
__global__ __launch_bounds__(256) void transform_mfma_kernel(
    const ushort* __restrict__ xbA, const ushort* __restrict__ xbB,
    const ushort* __restrict__ mbA, const ushort* __restrict__ mbB,
    const ushort* __restrict__ wb, const float* __restrict__ b1,
    const float* __restrict__ b2, ushort* __restrict__ tbA,
    ushort* __restrict__ tbB, float* __restrict__ rA,
    float* __restrict__ rB) {
    __shared__ ushort hlds[4][16 * 72];
    int lane = threadIdx.x & 63;
    int wid = threadIdx.x >> 6;
    int l15 = lane & 15, lhi = lane >> 4;

    const ushort* w1l = wb;
    const ushort* w1r = wb + 2048;
    const ushort* w2l = wb + 4096;
    const ushort* w2r = wb + 6144;

    bf16x8 B1l[4], B1r[4];
#pragma unroll
    for (int jt = 0; jt < 4; ++jt) {
        B1l[jt] = *(const bf16x8*)&w1l[(jt * 16 + l15) * 32 + 8 * lhi];
        B1r[jt] = *(const bf16x8*)&w1r[(jt * 16 + l15) * 32 + 8 * lhi];
    }
    bf16x8 B2l[2][2], B2r[2][2];
#pragma unroll
    for (int ct = 0; ct < 2; ++ct)
#pragma unroll
        for (int kc = 0; kc < 2; ++kc) {
            B2l[ct][kc] = *(const bf16x8*)&w2l[(ct * 16 + l15) * 64 + kc * 32 + 8 * lhi];
            B2r[ct][kc] = *(const bf16x8*)&w2r[(ct * 16 + l15) * 64 + kc * 32 + 8 * lhi];
        }
    float bias1[4];
#pragma unroll
    for (int jt = 0; jt < 4; ++jt) bias1[jt] = b1[jt * 16 + l15];
    float bias2[2] = { b2[l15], b2[16 + l15] };

    ushort* hl = hlds[wid];

#pragma unroll
    for (int chunk = 0; chunk < 2; ++chunk) {
        int n0 = blockIdx.x * 128 + wid * 32 + chunk * 16;
        int nrow = n0 + l15;
        bf16x8 Am = {}, Ax = {};
        if (nrow < N_NODES) {
            const ushort* ms = (lhi < 2) ? mbA : mbB;
            const ushort* xs = (lhi < 2) ? xbA : xbB;
            Am = *(const bf16x8*)&ms[(size_t)nrow * 16 + 8 * (lhi & 1)];
            Ax = *(const bf16x8*)&xs[(size_t)nrow * 16 + 8 * (lhi & 1)];
        }
#pragma unroll
        for (int jt = 0; jt < 4; ++jt) {
            f32x4 acc = {};
            acc = __builtin_amdgcn_mfma_f32_16x16x32_bf16(Am, B1l[jt], acc, 0, 0, 0);
            acc = __builtin_amdgcn_mfma_f32_16x16x32_bf16(Ax, B1r[jt], acc, 0, 0, 0);
#pragma unroll
            for (int reg = 0; reg < 4; ++reg) {
                float h = fmaxf(acc[reg] + bias1[jt], 0.0f);
                hl[(lhi * 4 + reg) * 72 + jt * 16 + l15] = f2bf(h);
            }
        }
        bf16x8 Ah0 = *(const bf16x8*)&hl[l15 * 72 + 8 * lhi];
        bf16x8 Ah1 = *(const bf16x8*)&hl[l15 * 72 + 32 + 8 * lhi];
#pragma unroll
        for (int ct = 0; ct < 2; ++ct) {
            f32x4 acc = {};
            acc = __builtin_amdgcn_mfma_f32_16x16x32_bf16(Ah0, B2l[ct][0], acc, 0, 0, 0);
            acc = __builtin_amdgcn_mfma_f32_16x16x32_bf16(Ah1, B2l[ct][1], acc, 0, 0, 0);
            ushort* tdst = ct ? tbB : tbA;
#pragma unroll
            for (int reg = 0; reg < 4; ++reg) {
                int nr = n0 + lhi * 4 + reg;
                if (nr < N_NODES)
                    tdst[(size_t)nr * 16 + l15] = f2bf(acc[reg]);
            }
        }
#pragma unroll
        for (int ct = 0; ct < 2; ++ct) {
            f32x4 acc = {};
            acc = __builtin_amdgcn_mfma_f32_16x16x32_bf16(Ah0, B2r[ct][0], acc, 0, 0, 0);
            acc = __builtin_amdgcn_mfma_f32_16x16x32_bf16(Ah1, B2r[ct][1], acc, 0, 0, 0);
            float* rdst = ct ? rB : rA;
#pragma unroll
            for (int reg = 0; reg < 4; ++reg) {
                int nr = n0 + lhi * 4 + reg;
                if (nr < N_NODES)
                    rdst[(size_t)nr * 16 + l15] = acc[reg] + bias2[ct];
            }
        }
    }
}

// ---- launch -------------------------------------------------------------

extern "C" void kernel_launch(void* const* d_in, const int* in_sizes, int n_in,
                              void* d_out, int out_size, void* d_ws, size_t ws_size,
                              hipStream_t stream) {
    const float* x   = (const float*)d_in[0];
    const float* W1l = (const float*)d_in[1];
    const float* W1r = (const float*)d_in[2];
    const float* b1  = (const float*)d_in[3];
    const float* W2l = (const float*)d_in[4];
    const float* W2r = (const float*)d_in[5];
    const float* b2  = (const float*)d_in[6];
    const int*   ei  = (const int*)d_in[7];   // [2, N_EDGES]
    const int* src = ei;
    const int* dst = ei + N_EDGES;

    char* ws = (char*)d_ws;
    int*      bcnt   = (int*)ws;             ws += (size_t)(NB + 8) * 4;
    int*      counts = (int*)ws;             ws += (size_t)N_NODES * 4;
    int*      rowptr = (int*)ws;             ws += (size_t)N_NODES * 4;
    int*      perm   = (int*)ws;             ws += (size_t)NB * REG * 4;   // 7.2 MB
    unsigned* tmp    = (unsigned*)ws;        ws += (size_t)NB * REG * 4;   // 7.2 MB
    // mbA/mbB (3.2MB each) alias tmp (7.2MB): tmp dead after count_place.
    ushort*   mbA    = (ushort*)tmp;
    ushort*   mbB    = mbA + (size_t)N_NODES * 16;
    ushort*   xbA    = (ushort*)ws;          ws += (size_t)N_NODES * 16 * 2;
    ushort*   xbB    = (ushort*)ws;          ws += (size_t)N_NODES * 16 * 2;
    ushort*   wb     = (ushort*)ws;          ws += (size_t)8192 * 2;
    ushort*   tbA    = (ushort*)ws;          ws += (size_t)N_NODES * 16 * 2;
    ushort*   tbB    = (ushort*)ws;          ws += (size_t)N_NODES * 16 * 2;
    float*    rA     = (float*)ws;           ws += (size_t)N_NODES * 16 * 4;
    float*    rB     = (float*)ws;           ws += (size_t)N_NODES * 16 * 4;

    dim3 blk(256);

    cast_w_kernel<<<1, blk, 0, stream>>>(W1l, W1r, W2l, W2r, wb, bcnt);
    place_kernel<<<NBLK, blk, 0, stream>>>(src, dst, x, xbA, xbB, bcnt, tmp);
    count_place_kernel<<<NB, dim3(512), 0, stream>>>(tmp, bcnt, counts, rowptr, perm);

    gather_mean_kernel<<<2 * GSG8, blk, 0, stream>>>(xbA, xbB, rowptr, counts,
                                                     perm, mbA, mbB);
    transform_mfma_kernel<<<(N_NODES + 127) / 128, blk, 0, stream>>>(
        xbA, xbB, mbA, mbB, wb, b1, b2, tbA, tbB, rA, rB);
    gather_final_kernel<<<2 * GSG8, blk, 0, stream>>>(tbA, tbB, rowptr, counts,
                                                      perm, rA, rB, (float*)d_out);
}